// Round 3
// baseline (2707.585 us; speedup 1.0000x reference)
//
#include <hip/hip_runtime.h>
#include <math.h>

#define kD 2048
#define kH 32
#define kN 64
#define kS 2048

typedef unsigned short ushort_t;
typedef unsigned int uint32;

__device__ __forceinline__ ushort_t f2bf(float f) {
  uint32 u = __float_as_uint(f);
  u += 0x7fffu + ((u >> 16) & 1u);   // RNE
  return (ushort_t)(u >> 16);
}

// ---------------- LayerNorm (ln1) ----------------
__global__ __launch_bounds__(256) void ln1_kernel(
    const float* __restrict__ x, const float* __restrict__ w, const float* __restrict__ b,
    float* __restrict__ xn, float* __restrict__ state1_out)
{
  int t = blockIdx.x;
  const float* row = x + (size_t)t * kD;
  float s = 0.f, s2 = 0.f;
  for (int d = threadIdx.x; d < kD; d += 256) {
    float v = row[d]; s += v; s2 += v * v;
  }
  #pragma unroll
  for (int o = 32; o > 0; o >>= 1) { s += __shfl_down(s, o); s2 += __shfl_down(s2, o); }
  __shared__ float ls[4], ls2[4];
  int wid = threadIdx.x >> 6;
  if ((threadIdx.x & 63) == 0) { ls[wid] = s; ls2[wid] = s2; }
  __syncthreads();
  s = ls[0] + ls[1] + ls[2] + ls[3];
  s2 = ls2[0] + ls2[1] + ls2[2] + ls2[3];
  float mean = s * (1.f / kD);
  float var = s2 * (1.f / kD) - mean * mean;
  float rstd = rsqrtf(var + 1e-5f);
  float* orow = xn + (size_t)t * kD;
  for (int d = threadIdx.x; d < kD; d += 256) {
    float v = (row[d] - mean) * rstd * w[d] + b[d];
    orow[d] = v;
    if (t == kS - 1) state1_out[d] = v;
  }
}

// ---------------- mix + bf16 convert for r/k/v GEMM A operands ----------------
__global__ __launch_bounds__(256) void mix3_cvt(
    const float* __restrict__ xn, const float* __restrict__ s1,
    const float* __restrict__ cr, const float* __restrict__ ck, const float* __restrict__ cv,
    ushort_t* __restrict__ Ar, ushort_t* __restrict__ Ak, ushort_t* __restrict__ Av)
{
  int t = blockIdx.x;
  const float* cur = xn + (size_t)t * kD;
  const float* prv = (t > 0) ? (cur - kD) : s1;
  size_t base = (size_t)t * kD;
  for (int d = threadIdx.x; d < kD; d += 256) {
    float c = cur[d];
    float dx = prv[d] - c;
    Ar[base + d] = f2bf(c + dx * cr[d]);
    Ak[base + d] = f2bf(c + dx * ck[d]);
    Av[base + d] = f2bf(c + dx * cv[d]);
  }
}

// ---------------- batched fp32 -> bf16 ----------------
struct CvtArgs { const float* src[3]; ushort_t* dst[3]; };
__global__ __launch_bounds__(256) void cvt_bf16_b(CvtArgs args)
{
  const float* in = args.src[blockIdx.y];
  ushort_t* out = args.dst[blockIdx.y];
  int idx = blockIdx.x * 256 + threadIdx.x;   // one float4 per thread
  float4 v = ((const float4*)in)[idx];
  ushort_t o[4] = { f2bf(v.x), f2bf(v.y), f2bf(v.z), f2bf(v.w) };
  ((uint2*)out)[idx] = *(const uint2*)o;
}

// ---------------- batched bf16 MFMA NT GEMM ----------------
typedef __bf16 bf16x8 __attribute__((ext_vector_type(8)));
typedef float f32x4 __attribute__((ext_vector_type(4)));

struct GemmArgs {
  const ushort_t* A[3];
  const ushort_t* B[3];
  float* C[3];
  const float* resid[3];
};

__global__ __launch_bounds__(256) void gemm_bf16_b(GemmArgs args)
{
  int z = blockIdx.z;
  const ushort_t* __restrict__ A = args.A[z];
  const ushort_t* __restrict__ B = args.B[z];
  float* __restrict__ C = args.C[z];
  const float* __restrict__ resid = args.resid[z];

  __shared__ __align__(16) ushort_t As[128 * 64];
  __shared__ __align__(16) ushort_t Bs[128 * 64];
  int tid = threadIdx.x;
  int w = tid >> 6, lane = tid & 63;
  int row0 = blockIdx.y * 128, col0 = blockIdx.x * 128;
  int wrow = (w >> 1) * 64, wcol = (w & 1) * 64;
  int quad = lane >> 4, r16 = lane & 15;
  f32x4 acc[4][4] = {};

  int lrow = lane >> 3;
  int lsw  = (lane & 7) ^ lrow;

  for (int k0 = 0; k0 < kD; k0 += 64) {
    #pragma unroll
    for (int n = 0; n < 4; n++) {
      int rr = w * 32 + n * 8 + lrow;
      int cc = k0 + lsw * 8;
      const ushort_t* ga = A + (size_t)(row0 + rr) * kD + cc;
      const ushort_t* gb = B + (size_t)(col0 + rr) * kD + cc;
      __builtin_amdgcn_global_load_lds(
          (const __attribute__((address_space(1))) uint32*)ga,
          (__attribute__((address_space(3))) uint32*)&As[(w * 32 + n * 8) * 64], 16, 0, 0);
      __builtin_amdgcn_global_load_lds(
          (const __attribute__((address_space(1))) uint32*)gb,
          (__attribute__((address_space(3))) uint32*)&Bs[(w * 32 + n * 8) * 64], 16, 0, 0);
    }
    __syncthreads();
    #pragma unroll
    for (int kk = 0; kk < 64; kk += 32) {
      bf16x8 af[4], bfr[4];
      #pragma unroll
      for (int i = 0; i < 4; i++) {
        int row = wrow + i * 16 + r16;
        int chunk = ((kk >> 3) + quad) ^ (r16 & 7);
        af[i] = *(const bf16x8*)&As[row * 64 + chunk * 8];
      }
      #pragma unroll
      for (int j = 0; j < 4; j++) {
        int row = wcol + j * 16 + r16;
        int chunk = ((kk >> 3) + quad) ^ (r16 & 7);
        bfr[j] = *(const bf16x8*)&Bs[row * 64 + chunk * 8];
      }
      #pragma unroll
      for (int i = 0; i < 4; i++)
        #pragma unroll
        for (int j = 0; j < 4; j++)
          acc[i][j] = __builtin_amdgcn_mfma_f32_16x16x32_bf16(af[i], bfr[j], acc[i][j], 0, 0, 0);
    }
    __syncthreads();
  }
  #pragma unroll
  for (int i = 0; i < 4; i++) {
    #pragma unroll
    for (int j = 0; j < 4; j++) {
      int col = col0 + wcol + j * 16 + r16;
      #pragma unroll
      for (int reg = 0; reg < 4; reg++) {
        int row = row0 + wrow + i * 16 + quad * 4 + reg;
        float v = acc[i][j][reg];
        if (resid) v += resid[(size_t)row * kD + col];
        C[(size_t)row * kD + col] = v;
      }
    }
  }
}

// ---------------- fused small MLPs: 4 tokens/block, one launch, 4 modes ------
// MODE 0: gate = sigmoid(h) @ W2
// MODE 1: a    = sigmoid(h @ W2 + bias)
// MODE 2: wdec = exp(-0.606531*sigmoid(tanh(h) @ W2 + bias))
// MODE 3: v    = v + (vfirst - v)*sigmoid(h @ W2 + bias)   (in place on out)
template<int L, int MODE>
__device__ void mlp_body(int t0,
    const float* __restrict__ xn, const float* __restrict__ s1, const float* __restrict__ mixc,
    const float* __restrict__ W1, const float* __restrict__ W2, const float* __restrict__ bias,
    float* __restrict__ out, const float* __restrict__ vfirst,
    float* xm, float* hp, float* hsh)
{
  int tid = threadIdx.x;
  #pragma unroll
  for (int tl = 0; tl < 4; tl++) {
    int t = t0 + tl;
    const float* cur = xn + (size_t)t * kD;
    const float* prv = (t > 0) ? (cur - kD) : s1;
    for (int d = tid; d < kD; d += 256) {
      float c = cur[d];
      xm[tl * kD + d] = c + (prv[d] - c) * mixc[d];
    }
  }
  __syncthreads();
  constexpr int G = 256 / L;
  int l = tid % L;
  int sub = tid / L;
  float acc[4] = {0.f, 0.f, 0.f, 0.f};
  for (int d = sub; d < kD; d += G) {
    float wv = W1[(size_t)d * L + l];
    #pragma unroll
    for (int tl = 0; tl < 4; tl++) acc[tl] = fmaf(xm[tl * kD + d], wv, acc[tl]);
  }
  #pragma unroll
  for (int tl = 0; tl < 4; tl++) hp[tid * 4 + tl] = acc[tl];
  __syncthreads();
  if (tid < L) {
    #pragma unroll
    for (int tl = 0; tl < 4; tl++) {
      float s = 0.f;
      #pragma unroll
      for (int g = 0; g < G; g++) s += hp[(g * L + tid) * 4 + tl];
      if (MODE == 0) s = 1.f / (1.f + __expf(-s));
      else if (MODE == 2) s = tanhf(s);
      hsh[tl * L + tid] = s;
    }
  }
  __syncthreads();
  for (int d0 = tid; d0 < kD; d0 += 256) {
    float s[4] = {0.f, 0.f, 0.f, 0.f};
    for (int l2 = 0; l2 < L; l2++) {
      float wv = W2[(size_t)l2 * kD + d0];
      #pragma unroll
      for (int tl = 0; tl < 4; tl++) s[tl] = fmaf(hsh[tl * L + l2], wv, s[tl]);
    }
    #pragma unroll
    for (int tl = 0; tl < 4; tl++) {
      size_t off = (size_t)(t0 + tl) * kD + d0;
      if (MODE == 0) {
        out[off] = s[tl];
      } else if (MODE == 1) {
        out[off] = 1.f / (1.f + __expf(-(s[tl] + bias[d0])));
      } else if (MODE == 2) {
        float sg = 1.f / (1.f + __expf(-(s[tl] + bias[d0])));
        out[off] = __expf(-0.606531f * sg);
      } else {
        float sg = 1.f / (1.f + __expf(-(s[tl] + bias[d0])));
        float vv = out[off];
        out[off] = vv + (vfirst[off] - vv) * sg;
      }
    }
  }
}

__global__ __launch_bounds__(256) void mlp_all(
    const float* __restrict__ xn, const float* __restrict__ s1,
    const float* __restrict__ cg, const float* __restrict__ ca,
    const float* __restrict__ cw, const float* __restrict__ cv,
    const float* __restrict__ g1, const float* __restrict__ g2,
    const float* __restrict__ a1, const float* __restrict__ a2, const float* __restrict__ a0,
    const float* __restrict__ w1, const float* __restrict__ w2, const float* __restrict__ w0,
    const float* __restrict__ v1, const float* __restrict__ v2, const float* __restrict__ v0,
    float* __restrict__ gB, float* __restrict__ aB, float* __restrict__ wB,
    float* __restrict__ vB, const float* __restrict__ vfirst)
{
  __shared__ float xm[4 * kD];
  __shared__ float hp[256 * 4];
  __shared__ float hsh[4 * 128];
  int t0 = blockIdx.x * 4;
  switch (blockIdx.y) {
    case 0:  mlp_body<128, 0>(t0, xn, s1, cg, g1, g2, nullptr, gB, nullptr, xm, hp, hsh); break;
    case 1:  mlp_body<64, 1>(t0, xn, s1, ca, a1, a2, a0, aB, nullptr, xm, hp, hsh); break;
    case 2:  mlp_body<64, 2>(t0, xn, s1, cw, w1, w2, w0, wB, nullptr, xm, hp, hsh); break;
    default: mlp_body<32, 3>(t0, xn, s1, cv, v1, v2, v0, vB, vfirst, xm, hp, hsh); break;
  }
}

// ---------------- post: kk (normalized), k update, b ----------------
__global__ __launch_bounds__(256) void post_kernel(
    float* __restrict__ kArr, float* __restrict__ kkArr, float* __restrict__ bArr,
    const float* __restrict__ aArr, const float* __restrict__ k_k, const float* __restrict__ k_a)
{
  int gid = blockIdx.x * 4 + (threadIdx.x >> 6);
  int lane = threadIdx.x & 63;
  int h = gid & (kH - 1);
  size_t off = (size_t)gid * kN + lane;
  float kv = kArr[off];
  float kkv = kv * k_k[h * kN + lane];
  float ss = kkv * kkv;
  #pragma unroll
  for (int o = 32; o > 0; o >>= 1) ss += __shfl_xor(ss, o);
  float scale = 1.f / fmaxf(sqrtf(ss), 1e-12f);
  float kkf = kkv * scale;
  kkArr[off] = kkf;
  float av = aArr[off];
  bArr[off] = kkf * av;
  kArr[off] = kv * (1.f + (av - 1.f) * k_a[h * kN + lane]);
}

// ---------------- sequential scan: producer/consumer waves + LDS ring --------
// Block = 128 threads: wave 0 computes, wave 1 streams step vectors into a
// 24-slot LDS ring via global_load_lds (async DMA, no VGPR round trip).
// Phases of 8 steps; producer runs 2 phases (16..24 steps) ahead. The
// compiler's vmcnt(0)-before-s_barrier drain guarantees slot visibility.
#define SLOT_F 336   // floats per ring slot (5*64 vectors + 8 v + pad)
#define NSLOT 24

#define DOT8(x0, x1, y0, y1) \
  ((x0).x*(y0).x + (x0).y*(y0).y + (x0).z*(y0).z + (x0).w*(y0).w + \
   (x1).x*(y1).x + (x1).y*(y1).y + (x1).z*(y1).z + (x1).w*(y1).w)

__global__ __launch_bounds__(128) void scan_kernel(
    const float* __restrict__ s0_in, const float* __restrict__ rA, const float* __restrict__ wA,
    const float* __restrict__ kA, const float* __restrict__ vA, const float* __restrict__ kkA,
    const float* __restrict__ bA, float* __restrict__ y, float* __restrict__ s_out)
{
  __shared__ __align__(16) float ring[NSLOT * SLOT_F];
  int blk = blockIdx.x;
  int h = blk >> 3;
  int i0 = (blk & 7) << 3;
  int wid = threadIdx.x >> 6;
  int lane = threadIdx.x & 63;
  int hv = h * kN;

  if (wid == 1) {
    // -------- producer --------
    const float* src0 = rA + hv;
    const float* src1 = wA + hv;
    const float* src2 = kA + hv;
    const float* src3 = kkA + hv;
    const float* src4 = bA + hv;
    const float* vsrc = vA + hv + i0;
    int slot = 0;
    #define ISSUE(t)                                                                     \
      {                                                                                  \
        float* sb = &ring[slot * SLOT_F];                                                \
        size_t go = (size_t)(t) * kD + lane;                                             \
        __builtin_amdgcn_global_load_lds(                                                \
            (const __attribute__((address_space(1))) uint32*)(src0 + go),                \
            (__attribute__((address_space(3))) uint32*)(sb + 0), 4, 0, 0);               \
        __builtin_amdgcn_global_load_lds(                                                \
            (const __attribute__((address_space(1))) uint32*)(src1 + go),                \
            (__attribute__((address_space(3))) uint32*)(sb + 64), 4, 0, 0);              \
        __builtin_amdgcn_global_load_lds(                                                \
            (const __attribute__((address_space(1))) uint32*)(src2 + go),                \
            (__attribute__((address_space(3))) uint32*)(sb + 128), 4, 0, 0);             \
        __builtin_amdgcn_global_load_lds(                                                \
            (const __attribute__((address_space(1))) uint32*)(src3 + go),                \
            (__attribute__((address_space(3))) uint32*)(sb + 192), 4, 0, 0);             \
        __builtin_amdgcn_global_load_lds(                                                \
            (const __attribute__((address_space(1))) uint32*)(src4 + go),                \
            (__attribute__((address_space(3))) uint32*)(sb + 256), 4, 0, 0);             \
        if (lane < 8)                                                                    \
          __builtin_amdgcn_global_load_lds(                                              \
              (const __attribute__((address_space(1))) uint32*)(vsrc + (size_t)(t) * kD + lane), \
              (__attribute__((address_space(3))) uint32*)(sb + 320), 4, 0, 0);           \
        slot++; if (slot == NSLOT) slot = 0;                                             \
      }
    for (int t = 0; t < 16; t++) ISSUE(t);
    __syncthreads();
    for (int ph = 0; ph < kS / 8; ph++) {
      int t0 = ph * 8 + 16;
      if (t0 < kS) {
        for (int s = 0; s < 8; s++) ISSUE(t0 + s);
      }
      __syncthreads();
    }
    #undef ISSUE
  } else {
    // -------- consumer --------
    __syncthreads();   // matches producer prologue barrier
    int q = lane & 7;
    int il = lane >> 3;
    int j0 = q << 3;
    size_t srow = ((size_t)(hv + i0 + il)) * kN + j0;
    float4 sSa = *(const float4*)(s0_in + srow);
    float4 sSb = *(const float4*)(s0_in + srow + 4);
    float* py = y + (size_t)(hv + i0 + il);

    float4 cur[10]; float curV;
    float4 nxt[10]; float nxtV;
    auto loadslot = [&](int sl, float4* dst, float& dV) {
      const float* sb = &ring[sl * SLOT_F];
      #pragma unroll
      for (int v5 = 0; v5 < 5; v5++) {
        dst[v5 * 2]     = *(const float4*)(sb + v5 * 64 + j0);
        dst[v5 * 2 + 1] = *(const float4*)(sb + v5 * 64 + j0 + 4);
      }
      dV = sb[320 + il];
    };
    loadslot(0, cur, curV);
    int slot = 1;
    for (int ph = 0; ph < kS / 8; ph++) {
      #pragma unroll
      for (int s = 0; s < 8; s++) {
        loadslot(slot, nxt, nxtV);
        slot++; if (slot == NSLOT) slot = 0;
        // slot layout: r=0,1  w=2,3  k=4,5  kk=6,7  b=8,9
        float sa = DOT8(sSa, sSb, cur[6], cur[7]);
        sa += __shfl_xor(sa, 1); sa += __shfl_xor(sa, 2); sa += __shfl_xor(sa, 4);
        sa = -sa;
        float vi = curV;
        sSa.x = fmaf(sSa.x, cur[2].x, fmaf(sa, cur[8].x, vi * cur[4].x));
        sSa.y = fmaf(sSa.y, cur[2].y, fmaf(sa, cur[8].y, vi * cur[4].y));
        sSa.z = fmaf(sSa.z, cur[2].z, fmaf(sa, cur[8].z, vi * cur[4].z));
        sSa.w = fmaf(sSa.w, cur[2].w, fmaf(sa, cur[8].w, vi * cur[4].w));
        sSb.x = fmaf(sSb.x, cur[3].x, fmaf(sa, cur[9].x, vi * cur[5].x));
        sSb.y = fmaf(sSb.y, cur[3].y, fmaf(sa, cur[9].y, vi * cur[5].y));
        sSb.z = fmaf(sSb.z, cur[3].z, fmaf(sa, cur[9].z, vi * cur[5].z));
        sSb.w = fmaf(sSb.w, cur[3].w, fmaf(sa, cur[9].w, vi * cur[5].w));
        float yv = DOT8(sSa, sSb, cur[0], cur[1]);
        yv += __shfl_xor(yv, 1); yv += __shfl_xor(yv, 2); yv += __shfl_xor(yv, 4);
        if (q == 0) *py = yv;
        py += kD;
        #pragma unroll
        for (int m = 0; m < 10; m++) cur[m] = nxt[m];
        curV = nxtV;
      }
      __syncthreads();
    }
    *(float4*)(s_out + srow) = sSa;
    *(float4*)(s_out + srow + 4) = sSb;
  }
}

// ---------------- output: groupnorm(y)*lnx + rkv, *gate → bf16 A for Wo -----
__global__ __launch_bounds__(256) void out_kernel(
    const float* __restrict__ y, const float* __restrict__ rA, const float* __restrict__ kA,
    const float* __restrict__ vA, const float* __restrict__ r_k,
    const float* __restrict__ lnw, const float* __restrict__ lnb,
    const float* __restrict__ gate, ushort_t* __restrict__ Ay)
{
  int gid = blockIdx.x * 4 + (threadIdx.x >> 6);
  int lane = threadIdx.x & 63;
  int h = gid & (kH - 1);
  size_t off = (size_t)gid * kN + lane;
  float yv = y[off];
  float s = yv, s2 = yv * yv;
  #pragma unroll
  for (int o = 32; o > 0; o >>= 1) { s += __shfl_xor(s, o); s2 += __shfl_xor(s2, o); }
  float mean = s * (1.f / kN);
  float var = s2 * (1.f / kN) - mean * mean;
  float o1 = (yv - mean) * rsqrtf(var + 0.00064f);
  int d = h * kN + lane;
  float ov = o1 * lnw[d] + lnb[d];
  float p = rA[off] * kA[off] * r_k[d];
  #pragma unroll
  for (int o = 32; o > 0; o >>= 1) p += __shfl_xor(p, o);
  float rkv = p * vA[off];
  Ay[off] = f2bf((ov + rkv) * gate[off]);
}

extern "C" void kernel_launch(void* const* d_in, const int* in_sizes, int n_in,
                              void* d_out, int out_size, void* d_ws, size_t ws_size,
                              hipStream_t stream)
{
  const float* x      = (const float*)d_in[0];
  const float* state1 = (const float*)d_in[1];
  const float* state2 = (const float*)d_in[2];
  const float* vfirst = (const float*)d_in[3];
  const float* ln1w   = (const float*)d_in[4];
  const float* ln1b   = (const float*)d_in[5];
  const float* xr_c   = (const float*)d_in[6];
  const float* xw_c   = (const float*)d_in[7];
  const float* xk_c   = (const float*)d_in[8];
  const float* xv_c   = (const float*)d_in[9];
  const float* xa_c   = (const float*)d_in[10];
  const float* xg_c   = (const float*)d_in[11];
  const float* Wr     = (const float*)d_in[12];
  const float* Wk     = (const float*)d_in[13];
  const float* Wv     = (const float*)d_in[14];
  const float* Wo     = (const float*)d_in[15];
  const float* w1     = (const float*)d_in[16];
  const float* w2     = (const float*)d_in[17];
  const float* w0     = (const float*)d_in[18];
  const float* a1     = (const float*)d_in[19];
  const float* a2     = (const float*)d_in[20];
  const float* a0     = (const float*)d_in[21];
  const float* g1     = (const float*)d_in[22];
  const float* g2     = (const float*)d_in[23];
  const float* v1     = (const float*)d_in[24];
  const float* v2     = (const float*)d_in[25];
  const float* v0     = (const float*)d_in[26];
  const float* k_k    = (const float*)d_in[27];
  const float* k_a    = (const float*)d_in[28];
  const float* r_k    = (const float*)d_in[29];
  const float* lnxw   = (const float*)d_in[30];
  const float* lnxb   = (const float*)d_in[31];

  float* out0  = (float*)d_out;
  float* s1out = out0 + (size_t)kS * kD;
  float* s2out = s1out + kD;

  size_t SD = (size_t)kS * kD;
  float* ws  = (float*)d_ws;
  float* xnB = ws;
  float* rB  = ws + SD;
  float* kB  = ws + 2 * SD;
  float* vB  = ws + 3 * SD;
  float* wB  = ws + 4 * SD;
  float* aB  = ws + 5 * SD;
  float* kkB = ws + 6 * SD;
  float* bB  = ws + 7 * SD;
  float* gB  = ws + 8 * SD;
  float* yB  = ws + 9 * SD;
  // bf16 overlays on temporarily-dead fp32 regions
  ushort_t* ArB = (ushort_t*)kkB;        // dead until post_kernel
  ushort_t* AkB = (ushort_t*)kkB + SD;
  ushort_t* AvB = (ushort_t*)bB;
  ushort_t* WrB = (ushort_t*)yB;         // dead until scan
  ushort_t* WkB = (ushort_t*)yB + SD;
  ushort_t* WvB = (ushort_t*)gB;         // dead until mlp_all
  ushort_t* AyB = (ushort_t*)aB;         // dead after post_kernel
  ushort_t* WoB = (ushort_t*)rB;         // dead after out_kernel

  ln1_kernel<<<kS, 256, 0, stream>>>(x, ln1w, ln1b, xnB, s1out);
  mix3_cvt<<<kS, 256, 0, stream>>>(xnB, state1, xr_c, xk_c, xv_c, ArB, AkB, AvB);

  const int CVT_BLKS = (int)(SD / 4 / 256);
  {
    CvtArgs ca;
    ca.src[0] = Wr; ca.src[1] = Wk; ca.src[2] = Wv;
    ca.dst[0] = WrB; ca.dst[1] = WkB; ca.dst[2] = WvB;
    cvt_bf16_b<<<dim3(CVT_BLKS, 3), 256, 0, stream>>>(ca);
  }
  {
    GemmArgs ga;
    ga.A[0] = ArB; ga.A[1] = AkB; ga.A[2] = AvB;
    ga.B[0] = WrB; ga.B[1] = WkB; ga.B[2] = WvB;
    ga.C[0] = rB;  ga.C[1] = kB;  ga.C[2] = vB;
    ga.resid[0] = nullptr; ga.resid[1] = nullptr; ga.resid[2] = nullptr;
    gemm_bf16_b<<<dim3(16, 16, 3), 256, 0, stream>>>(ga);
  }

  mlp_all<<<dim3(kS / 4, 4), 256, 0, stream>>>(
      xnB, state1, xg_c, xa_c, xw_c, xv_c,
      g1, g2, a1, a2, a0, w1, w2, w0, v1, v2, v0,
      gB, aB, wB, vB, vfirst);

  post_kernel<<<kS * kH / 4, 256, 0, stream>>>(kB, kkB, bB, aB, k_k, k_a);

  scan_kernel<<<kH * 8, 128, 0, stream>>>(state2, rB, wB, kB, vB, kkB, bB, yB, s2out);

  out_kernel<<<kS * kH / 4, 256, 0, stream>>>(yB, rB, kB, vB, r_k, lnxw, lnxb, gB, AyB);

  {
    CvtArgs ca;
    ca.src[0] = Wo; ca.src[1] = Wo; ca.src[2] = Wo;
    ca.dst[0] = WoB; ca.dst[1] = WoB; ca.dst[2] = WoB;
    cvt_bf16_b<<<dim3(CVT_BLKS, 1), 256, 0, stream>>>(ca);
  }
  {
    GemmArgs ga;
    ga.A[0] = AyB; ga.A[1] = AyB; ga.A[2] = AyB;
    ga.B[0] = WoB; ga.B[1] = WoB; ga.B[2] = WoB;
    ga.C[0] = out0; ga.C[1] = out0; ga.C[2] = out0;
    ga.resid[0] = x; ga.resid[1] = x; ga.resid[2] = x;
    gemm_bf16_b<<<dim3(16, 16, 1), 256, 0, stream>>>(ga);
  }
}

// Round 4
// 1377.805 us; speedup vs baseline: 1.9651x; 1.9651x over previous
//
#include <hip/hip_runtime.h>
#include <math.h>

#define kD 2048
#define kH 32
#define kN 64
#define kS 2048

typedef unsigned short ushort_t;
typedef unsigned int uint32;

__device__ __forceinline__ ushort_t f2bf(float f) {
  uint32 u = __float_as_uint(f);
  u += 0x7fffu + ((u >> 16) & 1u);   // RNE
  return (ushort_t)(u >> 16);
}

// ---------------- LayerNorm (ln1) ----------------
__global__ __launch_bounds__(256) void ln1_kernel(
    const float* __restrict__ x, const float* __restrict__ w, const float* __restrict__ b,
    float* __restrict__ xn, float* __restrict__ state1_out)
{
  int t = blockIdx.x;
  const float* row = x + (size_t)t * kD;
  float s = 0.f, s2 = 0.f;
  for (int d = threadIdx.x; d < kD; d += 256) {
    float v = row[d]; s += v; s2 += v * v;
  }
  #pragma unroll
  for (int o = 32; o > 0; o >>= 1) { s += __shfl_down(s, o); s2 += __shfl_down(s2, o); }
  __shared__ float ls[4], ls2[4];
  int wid = threadIdx.x >> 6;
  if ((threadIdx.x & 63) == 0) { ls[wid] = s; ls2[wid] = s2; }
  __syncthreads();
  s = ls[0] + ls[1] + ls[2] + ls[3];
  s2 = ls2[0] + ls2[1] + ls2[2] + ls2[3];
  float mean = s * (1.f / kD);
  float var = s2 * (1.f / kD) - mean * mean;
  float rstd = rsqrtf(var + 1e-5f);
  float* orow = xn + (size_t)t * kD;
  for (int d = threadIdx.x; d < kD; d += 256) {
    float v = (row[d] - mean) * rstd * w[d] + b[d];
    orow[d] = v;
    if (t == kS - 1) state1_out[d] = v;
  }
}

// ---------------- mix + bf16 convert for r/k/v GEMM A operands ----------------
__global__ __launch_bounds__(256) void mix3_cvt(
    const float* __restrict__ xn, const float* __restrict__ s1,
    const float* __restrict__ cr, const float* __restrict__ ck, const float* __restrict__ cv,
    ushort_t* __restrict__ Ar, ushort_t* __restrict__ Ak, ushort_t* __restrict__ Av)
{
  int t = blockIdx.x;
  const float* cur = xn + (size_t)t * kD;
  const float* prv = (t > 0) ? (cur - kD) : s1;
  size_t base = (size_t)t * kD;
  for (int d = threadIdx.x; d < kD; d += 256) {
    float c = cur[d];
    float dx = prv[d] - c;
    Ar[base + d] = f2bf(c + dx * cr[d]);
    Ak[base + d] = f2bf(c + dx * ck[d]);
    Av[base + d] = f2bf(c + dx * cv[d]);
  }
}

// ---------------- batched fp32 -> bf16 ----------------
struct CvtArgs { const float* src[3]; ushort_t* dst[3]; };
__global__ __launch_bounds__(256) void cvt_bf16_b(CvtArgs args)
{
  const float* in = args.src[blockIdx.y];
  ushort_t* out = args.dst[blockIdx.y];
  int idx = blockIdx.x * 256 + threadIdx.x;   // one float4 per thread
  float4 v = ((const float4*)in)[idx];
  ushort_t o[4] = { f2bf(v.x), f2bf(v.y), f2bf(v.z), f2bf(v.w) };
  ((uint2*)out)[idx] = *(const uint2*)o;
}

// ---------------- batched bf16 MFMA NT GEMM ----------------
typedef __bf16 bf16x8 __attribute__((ext_vector_type(8)));
typedef float f32x4 __attribute__((ext_vector_type(4)));

struct GemmArgs {
  const ushort_t* A[3];
  const ushort_t* B[3];
  float* C[3];
  const float* resid[3];
};

__global__ __launch_bounds__(256) void gemm_bf16_b(GemmArgs args)
{
  int z = blockIdx.z;
  const ushort_t* __restrict__ A = args.A[z];
  const ushort_t* __restrict__ B = args.B[z];
  float* __restrict__ C = args.C[z];
  const float* __restrict__ resid = args.resid[z];

  __shared__ __align__(16) ushort_t As[128 * 64];
  __shared__ __align__(16) ushort_t Bs[128 * 64];
  int tid = threadIdx.x;
  int w = tid >> 6, lane = tid & 63;
  int row0 = blockIdx.y * 128, col0 = blockIdx.x * 128;
  int wrow = (w >> 1) * 64, wcol = (w & 1) * 64;
  int quad = lane >> 4, r16 = lane & 15;
  f32x4 acc[4][4] = {};

  int lrow = lane >> 3;
  int lsw  = (lane & 7) ^ lrow;

  for (int k0 = 0; k0 < kD; k0 += 64) {
    #pragma unroll
    for (int n = 0; n < 4; n++) {
      int rr = w * 32 + n * 8 + lrow;
      int cc = k0 + lsw * 8;
      const ushort_t* ga = A + (size_t)(row0 + rr) * kD + cc;
      const ushort_t* gb = B + (size_t)(col0 + rr) * kD + cc;
      __builtin_amdgcn_global_load_lds(
          (const __attribute__((address_space(1))) uint32*)ga,
          (__attribute__((address_space(3))) uint32*)&As[(w * 32 + n * 8) * 64], 16, 0, 0);
      __builtin_amdgcn_global_load_lds(
          (const __attribute__((address_space(1))) uint32*)gb,
          (__attribute__((address_space(3))) uint32*)&Bs[(w * 32 + n * 8) * 64], 16, 0, 0);
    }
    __syncthreads();
    #pragma unroll
    for (int kk = 0; kk < 64; kk += 32) {
      bf16x8 af[4], bfr[4];
      #pragma unroll
      for (int i = 0; i < 4; i++) {
        int row = wrow + i * 16 + r16;
        int chunk = ((kk >> 3) + quad) ^ (r16 & 7);
        af[i] = *(const bf16x8*)&As[row * 64 + chunk * 8];
      }
      #pragma unroll
      for (int j = 0; j < 4; j++) {
        int row = wcol + j * 16 + r16;
        int chunk = ((kk >> 3) + quad) ^ (r16 & 7);
        bfr[j] = *(const bf16x8*)&Bs[row * 64 + chunk * 8];
      }
      #pragma unroll
      for (int i = 0; i < 4; i++)
        #pragma unroll
        for (int j = 0; j < 4; j++)
          acc[i][j] = __builtin_amdgcn_mfma_f32_16x16x32_bf16(af[i], bfr[j], acc[i][j], 0, 0, 0);
    }
    __syncthreads();
  }
  #pragma unroll
  for (int i = 0; i < 4; i++) {
    #pragma unroll
    for (int j = 0; j < 4; j++) {
      int col = col0 + wcol + j * 16 + r16;
      #pragma unroll
      for (int reg = 0; reg < 4; reg++) {
        int row = row0 + wrow + i * 16 + quad * 4 + reg;
        float v = acc[i][j][reg];
        if (resid) v += resid[(size_t)row * kD + col];
        C[(size_t)row * kD + col] = v;
      }
    }
  }
}

// ---------------- fused small MLP per token (round-2 proven version) ---------
// MODE 0: gate = sigmoid(h) @ W2
// MODE 1: a    = sigmoid(h @ W2 + bias)
// MODE 2: wdec = exp(-0.606531*sigmoid(tanh(h) @ W2 + bias))
// MODE 3: v    = v + (vfirst - v)*sigmoid(h @ W2 + bias)   (in place on out)
template<int L, int MODE>
__global__ __launch_bounds__(256) void mlp_kernel(
    const float* __restrict__ xn, const float* __restrict__ state1,
    const float* __restrict__ mixc, const float* __restrict__ W1,
    const float* __restrict__ W2, const float* __restrict__ bias,
    float* __restrict__ out, const float* __restrict__ vfirst)
{
  __shared__ float xm[kD];
  __shared__ float hsh[L];
  __shared__ float hp[256];
  int t = blockIdx.x;
  int tid = threadIdx.x;
  const float* cur = xn + (size_t)t * kD;
  const float* prv = (t > 0) ? (xn + (size_t)(t - 1) * kD) : state1;
  for (int d = tid; d < kD; d += 256) {
    float c = cur[d];
    xm[d] = c + (prv[d] - c) * mixc[d];
  }
  __syncthreads();
  constexpr int G = 256 / L;
  int l = tid % L;
  int sub = tid / L;
  float acc = 0.f;
  #pragma unroll 4
  for (int d = sub; d < kD; d += G) acc += xm[d] * W1[(size_t)d * L + l];
  hp[tid] = acc;
  __syncthreads();
  if (tid < L) {
    float s = 0.f;
    #pragma unroll
    for (int g = 0; g < G; g++) s += hp[g * L + tid];
    if (MODE == 0) s = 1.f / (1.f + __expf(-s));
    else if (MODE == 2) s = tanhf(s);
    hsh[tid] = s;
  }
  __syncthreads();
  for (int d0 = tid; d0 < kD; d0 += 256) {
    float s = 0.f;
    #pragma unroll 16
    for (int l2 = 0; l2 < L; l2++) s = fmaf(hsh[l2], W2[(size_t)l2 * kD + d0], s);
    size_t off = (size_t)t * kD + d0;
    if (MODE == 0) {
      out[off] = s;
    } else if (MODE == 1) {
      out[off] = 1.f / (1.f + __expf(-(s + bias[d0])));
    } else if (MODE == 2) {
      float sg = 1.f / (1.f + __expf(-(s + bias[d0])));
      out[off] = __expf(-0.606531f * sg);
    } else {
      float sg = 1.f / (1.f + __expf(-(s + bias[d0])));
      float vv = out[off];
      out[off] = vv + (vfirst[off] - vv) * sg;
    }
  }
}

// ---------------- post: kk (normalized), k update, b ----------------
__global__ __launch_bounds__(256) void post_kernel(
    float* __restrict__ kArr, float* __restrict__ kkArr, float* __restrict__ bArr,
    const float* __restrict__ aArr, const float* __restrict__ k_k, const float* __restrict__ k_a)
{
  int gid = blockIdx.x * 4 + (threadIdx.x >> 6);
  int lane = threadIdx.x & 63;
  int h = gid & (kH - 1);
  size_t off = (size_t)gid * kN + lane;
  float kv = kArr[off];
  float kkv = kv * k_k[h * kN + lane];
  float ss = kkv * kkv;
  #pragma unroll
  for (int o = 32; o > 0; o >>= 1) ss += __shfl_xor(ss, o);
  float scale = 1.f / fmaxf(sqrtf(ss), 1e-12f);
  float kkf = kkv * scale;
  kkArr[off] = kkf;
  float av = aArr[off];
  bArr[off] = kkf * av;
  kArr[off] = kv * (1.f + (av - 1.f) * k_a[h * kN + lane]);
}

// ---------------- sequential scan: producer/consumer waves + LDS ring --------
#define SLOT_F 336   // floats per ring slot (5*64 vectors + 8 v + pad)
#define NSLOT 24

#define DOT8(x0, x1, y0, y1) \
  ((x0).x*(y0).x + (x0).y*(y0).y + (x0).z*(y0).z + (x0).w*(y0).w + \
   (x1).x*(y1).x + (x1).y*(y1).y + (x1).z*(y1).z + (x1).w*(y1).w)

__global__ __launch_bounds__(128) void scan_kernel(
    const float* __restrict__ s0_in, const float* __restrict__ rA, const float* __restrict__ wA,
    const float* __restrict__ kA, const float* __restrict__ vA, const float* __restrict__ kkA,
    const float* __restrict__ bA, float* __restrict__ y, float* __restrict__ s_out)
{
  __shared__ __align__(16) float ring[NSLOT * SLOT_F];
  int blk = blockIdx.x;
  int h = blk >> 3;
  int i0 = (blk & 7) << 3;
  int wid = threadIdx.x >> 6;
  int lane = threadIdx.x & 63;
  int hv = h * kN;

  if (wid == 1) {
    // -------- producer --------
    const float* src0 = rA + hv;
    const float* src1 = wA + hv;
    const float* src2 = kA + hv;
    const float* src3 = kkA + hv;
    const float* src4 = bA + hv;
    const float* vsrc = vA + hv + i0;
    int slot = 0;
    #define ISSUE(t)                                                                     \
      {                                                                                  \
        float* sb = &ring[slot * SLOT_F];                                                \
        size_t go = (size_t)(t) * kD + lane;                                             \
        __builtin_amdgcn_global_load_lds(                                                \
            (const __attribute__((address_space(1))) uint32*)(src0 + go),                \
            (__attribute__((address_space(3))) uint32*)(sb + 0), 4, 0, 0);               \
        __builtin_amdgcn_global_load_lds(                                                \
            (const __attribute__((address_space(1))) uint32*)(src1 + go),                \
            (__attribute__((address_space(3))) uint32*)(sb + 64), 4, 0, 0);              \
        __builtin_amdgcn_global_load_lds(                                                \
            (const __attribute__((address_space(1))) uint32*)(src2 + go),                \
            (__attribute__((address_space(3))) uint32*)(sb + 128), 4, 0, 0);             \
        __builtin_amdgcn_global_load_lds(                                                \
            (const __attribute__((address_space(1))) uint32*)(src3 + go),                \
            (__attribute__((address_space(3))) uint32*)(sb + 192), 4, 0, 0);             \
        __builtin_amdgcn_global_load_lds(                                                \
            (const __attribute__((address_space(1))) uint32*)(src4 + go),                \
            (__attribute__((address_space(3))) uint32*)(sb + 256), 4, 0, 0);             \
        if (lane < 8)                                                                    \
          __builtin_amdgcn_global_load_lds(                                              \
              (const __attribute__((address_space(1))) uint32*)(vsrc + (size_t)(t) * kD + lane), \
              (__attribute__((address_space(3))) uint32*)(sb + 320), 4, 0, 0);           \
        slot++; if (slot == NSLOT) slot = 0;                                             \
      }
    for (int t = 0; t < 16; t++) ISSUE(t);
    __syncthreads();
    for (int ph = 0; ph < kS / 8; ph++) {
      int t0 = ph * 8 + 16;
      if (t0 < kS) {
        for (int s = 0; s < 8; s++) ISSUE(t0 + s);
      }
      __syncthreads();
    }
    #undef ISSUE
  } else {
    // -------- consumer --------
    __syncthreads();   // matches producer prologue barrier
    int q = lane & 7;
    int il = lane >> 3;
    int j0 = q << 3;
    size_t srow = ((size_t)(hv + i0 + il)) * kN + j0;
    float4 sSa = *(const float4*)(s0_in + srow);
    float4 sSb = *(const float4*)(s0_in + srow + 4);
    float* py = y + (size_t)(hv + i0 + il);

    float4 cur[10]; float curV;
    float4 nxt[10]; float nxtV;
    auto loadslot = [&](int sl, float4* dst, float& dV) {
      const float* sb = &ring[sl * SLOT_F];
      #pragma unroll
      for (int v5 = 0; v5 < 5; v5++) {
        dst[v5 * 2]     = *(const float4*)(sb + v5 * 64 + j0);
        dst[v5 * 2 + 1] = *(const float4*)(sb + v5 * 64 + j0 + 4);
      }
      dV = sb[320 + il];
    };
    loadslot(0, cur, curV);
    int slot = 1;
    for (int ph = 0; ph < kS / 8; ph++) {
      #pragma unroll
      for (int s = 0; s < 8; s++) {
        loadslot(slot, nxt, nxtV);
        slot++; if (slot == NSLOT) slot = 0;
        // slot layout: r=0,1  w=2,3  k=4,5  kk=6,7  b=8,9
        float sa = DOT8(sSa, sSb, cur[6], cur[7]);
        sa += __shfl_xor(sa, 1); sa += __shfl_xor(sa, 2); sa += __shfl_xor(sa, 4);
        sa = -sa;
        float vi = curV;
        sSa.x = fmaf(sSa.x, cur[2].x, fmaf(sa, cur[8].x, vi * cur[4].x));
        sSa.y = fmaf(sSa.y, cur[2].y, fmaf(sa, cur[8].y, vi * cur[4].y));
        sSa.z = fmaf(sSa.z, cur[2].z, fmaf(sa, cur[8].z, vi * cur[4].z));
        sSa.w = fmaf(sSa.w, cur[2].w, fmaf(sa, cur[8].w, vi * cur[4].w));
        sSb.x = fmaf(sSb.x, cur[3].x, fmaf(sa, cur[9].x, vi * cur[5].x));
        sSb.y = fmaf(sSb.y, cur[3].y, fmaf(sa, cur[9].y, vi * cur[5].y));
        sSb.z = fmaf(sSb.z, cur[3].z, fmaf(sa, cur[9].z, vi * cur[5].z));
        sSb.w = fmaf(sSb.w, cur[3].w, fmaf(sa, cur[9].w, vi * cur[5].w));
        float yv = DOT8(sSa, sSb, cur[0], cur[1]);
        yv += __shfl_xor(yv, 1); yv += __shfl_xor(yv, 2); yv += __shfl_xor(yv, 4);
        if (q == 0) *py = yv;
        py += kD;
        #pragma unroll
        for (int m = 0; m < 10; m++) cur[m] = nxt[m];
        curV = nxtV;
      }
      __syncthreads();
    }
    *(float4*)(s_out + srow) = sSa;
    *(float4*)(s_out + srow + 4) = sSb;
  }
}

// ---------------- output: groupnorm(y)*lnx + rkv, *gate → bf16 A for Wo -----
__global__ __launch_bounds__(256) void out_kernel(
    const float* __restrict__ y, const float* __restrict__ rA, const float* __restrict__ kA,
    const float* __restrict__ vA, const float* __restrict__ r_k,
    const float* __restrict__ lnw, const float* __restrict__ lnb,
    const float* __restrict__ gate, ushort_t* __restrict__ Ay)
{
  int gid = blockIdx.x * 4 + (threadIdx.x >> 6);
  int lane = threadIdx.x & 63;
  int h = gid & (kH - 1);
  size_t off = (size_t)gid * kN + lane;
  float yv = y[off];
  float s = yv, s2 = yv * yv;
  #pragma unroll
  for (int o = 32; o > 0; o >>= 1) { s += __shfl_xor(s, o); s2 += __shfl_xor(s2, o); }
  float mean = s * (1.f / kN);
  float var = s2 * (1.f / kN) - mean * mean;
  float o1 = (yv - mean) * rsqrtf(var + 0.00064f);
  int d = h * kN + lane;
  float ov = o1 * lnw[d] + lnb[d];
  float p = rA[off] * kA[off] * r_k[d];
  #pragma unroll
  for (int o = 32; o > 0; o >>= 1) p += __shfl_xor(p, o);
  float rkv = p * vA[off];
  Ay[off] = f2bf((ov + rkv) * gate[off]);
}

extern "C" void kernel_launch(void* const* d_in, const int* in_sizes, int n_in,
                              void* d_out, int out_size, void* d_ws, size_t ws_size,
                              hipStream_t stream)
{
  const float* x      = (const float*)d_in[0];
  const float* state1 = (const float*)d_in[1];
  const float* state2 = (const float*)d_in[2];
  const float* vfirst = (const float*)d_in[3];
  const float* ln1w   = (const float*)d_in[4];
  const float* ln1b   = (const float*)d_in[5];
  const float* xr_c   = (const float*)d_in[6];
  const float* xw_c   = (const float*)d_in[7];
  const float* xk_c   = (const float*)d_in[8];
  const float* xv_c   = (const float*)d_in[9];
  const float* xa_c   = (const float*)d_in[10];
  const float* xg_c   = (const float*)d_in[11];
  const float* Wr     = (const float*)d_in[12];
  const float* Wk     = (const float*)d_in[13];
  const float* Wv     = (const float*)d_in[14];
  const float* Wo     = (const float*)d_in[15];
  const float* w1     = (const float*)d_in[16];
  const float* w2     = (const float*)d_in[17];
  const float* w0     = (const float*)d_in[18];
  const float* a1     = (const float*)d_in[19];
  const float* a2     = (const float*)d_in[20];
  const float* a0     = (const float*)d_in[21];
  const float* g1     = (const float*)d_in[22];
  const float* g2     = (const float*)d_in[23];
  const float* v1     = (const float*)d_in[24];
  const float* v2     = (const float*)d_in[25];
  const float* v0     = (const float*)d_in[26];
  const float* k_k    = (const float*)d_in[27];
  const float* k_a    = (const float*)d_in[28];
  const float* r_k    = (const float*)d_in[29];
  const float* lnxw   = (const float*)d_in[30];
  const float* lnxb   = (const float*)d_in[31];

  float* out0  = (float*)d_out;
  float* s1out = out0 + (size_t)kS * kD;
  float* s2out = s1out + kD;

  size_t SD = (size_t)kS * kD;
  float* ws  = (float*)d_ws;
  float* xnB = ws;
  float* rB  = ws + SD;
  float* kB  = ws + 2 * SD;
  float* vB  = ws + 3 * SD;
  float* wB  = ws + 4 * SD;
  float* aB  = ws + 5 * SD;
  float* kkB = ws + 6 * SD;
  float* bB  = ws + 7 * SD;
  float* gB  = ws + 8 * SD;
  float* yB  = ws + 9 * SD;
  // bf16 overlays on temporarily-dead fp32 regions
  ushort_t* ArB = (ushort_t*)kkB;        // dead until post_kernel
  ushort_t* AkB = (ushort_t*)kkB + SD;
  ushort_t* AvB = (ushort_t*)bB;
  ushort_t* WrB = (ushort_t*)yB;         // dead until scan
  ushort_t* WkB = (ushort_t*)yB + SD;
  ushort_t* WvB = (ushort_t*)gB;         // dead until mlp gate write
  ushort_t* AyB = (ushort_t*)aB;         // dead after post_kernel
  ushort_t* WoB = (ushort_t*)rB;         // dead after out_kernel

  ln1_kernel<<<kS, 256, 0, stream>>>(x, ln1w, ln1b, xnB, s1out);
  mix3_cvt<<<kS, 256, 0, stream>>>(xnB, state1, xr_c, xk_c, xv_c, ArB, AkB, AvB);

  const int CVT_BLKS = (int)(SD / 4 / 256);
  {
    CvtArgs ca;
    ca.src[0] = Wr; ca.src[1] = Wk; ca.src[2] = Wv;
    ca.dst[0] = WrB; ca.dst[1] = WkB; ca.dst[2] = WvB;
    cvt_bf16_b<<<dim3(CVT_BLKS, 3), 256, 0, stream>>>(ca);
  }
  {
    GemmArgs ga;
    ga.A[0] = ArB; ga.A[1] = AkB; ga.A[2] = AvB;
    ga.B[0] = WrB; ga.B[1] = WkB; ga.B[2] = WvB;
    ga.C[0] = rB;  ga.C[1] = kB;  ga.C[2] = vB;
    ga.resid[0] = nullptr; ga.resid[1] = nullptr; ga.resid[2] = nullptr;
    gemm_bf16_b<<<dim3(16, 16, 3), 256, 0, stream>>>(ga);
  }

  // round-2 proven per-token MLPs (gate first: it overwrites gB == WvB region
  // only after the z=3 GEMM above has consumed WvB)
  mlp_kernel<128, 0><<<kS, 256, 0, stream>>>(xnB, state1, xg_c, g1, g2, nullptr, gB, nullptr);
  mlp_kernel<64, 1><<<kS, 256, 0, stream>>>(xnB, state1, xa_c, a1, a2, a0, aB, nullptr);
  mlp_kernel<64, 2><<<kS, 256, 0, stream>>>(xnB, state1, xw_c, w1, w2, w0, wB, nullptr);
  mlp_kernel<32, 3><<<kS, 256, 0, stream>>>(xnB, state1, xv_c, v1, v2, v0, vB, vfirst);

  post_kernel<<<kS * kH / 4, 256, 0, stream>>>(kB, kkB, bB, aB, k_k, k_a);

  scan_kernel<<<kH * 8, 128, 0, stream>>>(state2, rB, wB, kB, vB, kkB, bB, yB, s2out);

  out_kernel<<<kS * kH / 4, 256, 0, stream>>>(yB, rB, kB, vB, r_k, lnxw, lnxb, gB, AyB);

  {
    CvtArgs ca;
    ca.src[0] = Wo; ca.src[1] = Wo; ca.src[2] = Wo;
    ca.dst[0] = WoB; ca.dst[1] = WoB; ca.dst[2] = WoB;
    cvt_bf16_b<<<dim3(CVT_BLKS, 1), 256, 0, stream>>>(ca);
  }
  {
    GemmArgs ga;
    ga.A[0] = AyB; ga.A[1] = AyB; ga.A[2] = AyB;
    ga.B[0] = WoB; ga.B[1] = WoB; ga.B[2] = WoB;
    ga.C[0] = out0; ga.C[1] = out0; ga.C[2] = out0;
    ga.resid[0] = x; ga.resid[1] = x; ga.resid[2] = x;
    gemm_bf16_b<<<dim3(16, 16, 1), 256, 0, stream>>>(ga);
  }
}

// Round 5
// 1119.707 us; speedup vs baseline: 2.4181x; 1.2305x over previous
//
#include <hip/hip_runtime.h>
#include <math.h>

#define kD 2048
#define kH 32
#define kN 64
#define kS 2048

typedef unsigned short ushort_t;
typedef unsigned int uint32;

__device__ __forceinline__ ushort_t f2bf(float f) {
  uint32 u = __float_as_uint(f);
  u += 0x7fffu + ((u >> 16) & 1u);   // RNE
  return (ushort_t)(u >> 16);
}

// ---------------- LayerNorm (ln1) ----------------
__global__ __launch_bounds__(256) void ln1_kernel(
    const float* __restrict__ x, const float* __restrict__ w, const float* __restrict__ b,
    float* __restrict__ xn, float* __restrict__ state1_out)
{
  int t = blockIdx.x;
  const float* row = x + (size_t)t * kD;
  float s = 0.f, s2 = 0.f;
  for (int d = threadIdx.x; d < kD; d += 256) {
    float v = row[d]; s += v; s2 += v * v;
  }
  #pragma unroll
  for (int o = 32; o > 0; o >>= 1) { s += __shfl_down(s, o); s2 += __shfl_down(s2, o); }
  __shared__ float ls[4], ls2[4];
  int wid = threadIdx.x >> 6;
  if ((threadIdx.x & 63) == 0) { ls[wid] = s; ls2[wid] = s2; }
  __syncthreads();
  s = ls[0] + ls[1] + ls[2] + ls[3];
  s2 = ls2[0] + ls2[1] + ls2[2] + ls2[3];
  float mean = s * (1.f / kD);
  float var = s2 * (1.f / kD) - mean * mean;
  float rstd = rsqrtf(var + 1e-5f);
  float* orow = xn + (size_t)t * kD;
  for (int d = threadIdx.x; d < kD; d += 256) {
    float v = (row[d] - mean) * rstd * w[d] + b[d];
    orow[d] = v;
    if (t == kS - 1) state1_out[d] = v;
  }
}

// ---------------- mix + bf16 convert for r/k/v GEMM A operands ----------------
__global__ __launch_bounds__(256) void mix3_cvt(
    const float* __restrict__ xn, const float* __restrict__ s1,
    const float* __restrict__ cr, const float* __restrict__ ck, const float* __restrict__ cv,
    ushort_t* __restrict__ Ar, ushort_t* __restrict__ Ak, ushort_t* __restrict__ Av)
{
  int t = blockIdx.x;
  const float* cur = xn + (size_t)t * kD;
  const float* prv = (t > 0) ? (cur - kD) : s1;
  size_t base = (size_t)t * kD;
  for (int d = threadIdx.x; d < kD; d += 256) {
    float c = cur[d];
    float dx = prv[d] - c;
    Ar[base + d] = f2bf(c + dx * cr[d]);
    Ak[base + d] = f2bf(c + dx * ck[d]);
    Av[base + d] = f2bf(c + dx * cv[d]);
  }
}

// ---------------- batched fp32 -> bf16 ----------------
struct CvtArgs { const float* src[3]; ushort_t* dst[3]; };
__global__ __launch_bounds__(256) void cvt_bf16_b(CvtArgs args)
{
  const float* in = args.src[blockIdx.y];
  ushort_t* out = args.dst[blockIdx.y];
  int idx = blockIdx.x * 256 + threadIdx.x;   // one float4 per thread
  float4 v = ((const float4*)in)[idx];
  ushort_t o[4] = { f2bf(v.x), f2bf(v.y), f2bf(v.z), f2bf(v.w) };
  ((uint2*)out)[idx] = *(const uint2*)o;
}

// ---------------- batched bf16 MFMA NT GEMM ----------------
typedef __bf16 bf16x8 __attribute__((ext_vector_type(8)));
typedef float f32x4 __attribute__((ext_vector_type(4)));

struct GemmArgs {
  const ushort_t* A[3];
  const ushort_t* B[3];
  float* C[3];
  const float* resid[3];
};

__global__ __launch_bounds__(256) void gemm_bf16_b(GemmArgs args)
{
  int z = blockIdx.z;
  const ushort_t* __restrict__ A = args.A[z];
  const ushort_t* __restrict__ B = args.B[z];
  float* __restrict__ C = args.C[z];
  const float* __restrict__ resid = args.resid[z];

  __shared__ __align__(16) ushort_t As[128 * 64];
  __shared__ __align__(16) ushort_t Bs[128 * 64];
  int tid = threadIdx.x;
  int w = tid >> 6, lane = tid & 63;
  int row0 = blockIdx.y * 128, col0 = blockIdx.x * 128;
  int wrow = (w >> 1) * 64, wcol = (w & 1) * 64;
  int quad = lane >> 4, r16 = lane & 15;
  f32x4 acc[4][4] = {};

  int lrow = lane >> 3;
  int lsw  = (lane & 7) ^ lrow;

  for (int k0 = 0; k0 < kD; k0 += 64) {
    #pragma unroll
    for (int n = 0; n < 4; n++) {
      int rr = w * 32 + n * 8 + lrow;
      int cc = k0 + lsw * 8;
      const ushort_t* ga = A + (size_t)(row0 + rr) * kD + cc;
      const ushort_t* gb = B + (size_t)(col0 + rr) * kD + cc;
      __builtin_amdgcn_global_load_lds(
          (const __attribute__((address_space(1))) uint32*)ga,
          (__attribute__((address_space(3))) uint32*)&As[(w * 32 + n * 8) * 64], 16, 0, 0);
      __builtin_amdgcn_global_load_lds(
          (const __attribute__((address_space(1))) uint32*)gb,
          (__attribute__((address_space(3))) uint32*)&Bs[(w * 32 + n * 8) * 64], 16, 0, 0);
    }
    __syncthreads();
    #pragma unroll
    for (int kk = 0; kk < 64; kk += 32) {
      bf16x8 af[4], bfr[4];
      #pragma unroll
      for (int i = 0; i < 4; i++) {
        int row = wrow + i * 16 + r16;
        int chunk = ((kk >> 3) + quad) ^ (r16 & 7);
        af[i] = *(const bf16x8*)&As[row * 64 + chunk * 8];
      }
      #pragma unroll
      for (int j = 0; j < 4; j++) {
        int row = wcol + j * 16 + r16;
        int chunk = ((kk >> 3) + quad) ^ (r16 & 7);
        bfr[j] = *(const bf16x8*)&Bs[row * 64 + chunk * 8];
      }
      #pragma unroll
      for (int i = 0; i < 4; i++)
        #pragma unroll
        for (int j = 0; j < 4; j++)
          acc[i][j] = __builtin_amdgcn_mfma_f32_16x16x32_bf16(af[i], bfr[j], acc[i][j], 0, 0, 0);
    }
    __syncthreads();
  }
  #pragma unroll
  for (int i = 0; i < 4; i++) {
    #pragma unroll
    for (int j = 0; j < 4; j++) {
      int col = col0 + wcol + j * 16 + r16;
      #pragma unroll
      for (int reg = 0; reg < 4; reg++) {
        int row = row0 + wrow + i * 16 + quad * 4 + reg;
        float v = acc[i][j][reg];
        if (resid) v += resid[(size_t)row * kD + col];
        C[(size_t)row * kD + col] = v;
      }
    }
  }
}

// ---------------- fused small MLP per token (round-2 proven version) ---------
template<int L, int MODE>
__global__ __launch_bounds__(256) void mlp_kernel(
    const float* __restrict__ xn, const float* __restrict__ state1,
    const float* __restrict__ mixc, const float* __restrict__ W1,
    const float* __restrict__ W2, const float* __restrict__ bias,
    float* __restrict__ out, const float* __restrict__ vfirst)
{
  __shared__ float xm[kD];
  __shared__ float hsh[L];
  __shared__ float hp[256];
  int t = blockIdx.x;
  int tid = threadIdx.x;
  const float* cur = xn + (size_t)t * kD;
  const float* prv = (t > 0) ? (xn + (size_t)(t - 1) * kD) : state1;
  for (int d = tid; d < kD; d += 256) {
    float c = cur[d];
    xm[d] = c + (prv[d] - c) * mixc[d];
  }
  __syncthreads();
  constexpr int G = 256 / L;
  int l = tid % L;
  int sub = tid / L;
  float acc = 0.f;
  #pragma unroll 4
  for (int d = sub; d < kD; d += G) acc += xm[d] * W1[(size_t)d * L + l];
  hp[tid] = acc;
  __syncthreads();
  if (tid < L) {
    float s = 0.f;
    #pragma unroll
    for (int g = 0; g < G; g++) s += hp[g * L + tid];
    if (MODE == 0) s = 1.f / (1.f + __expf(-s));
    else if (MODE == 2) s = tanhf(s);
    hsh[tid] = s;
  }
  __syncthreads();
  for (int d0 = tid; d0 < kD; d0 += 256) {
    float s = 0.f;
    #pragma unroll 16
    for (int l2 = 0; l2 < L; l2++) s = fmaf(hsh[l2], W2[(size_t)l2 * kD + d0], s);
    size_t off = (size_t)t * kD + d0;
    if (MODE == 0) {
      out[off] = s;
    } else if (MODE == 1) {
      out[off] = 1.f / (1.f + __expf(-(s + bias[d0])));
    } else if (MODE == 2) {
      float sg = 1.f / (1.f + __expf(-(s + bias[d0])));
      out[off] = __expf(-0.606531f * sg);
    } else {
      float sg = 1.f / (1.f + __expf(-(s + bias[d0])));
      float vv = out[off];
      out[off] = vv + (vfirst[off] - vv) * sg;
    }
  }
}

// ---------------- post: kk (normalized), k update, b ----------------
__global__ __launch_bounds__(256) void post_kernel(
    float* __restrict__ kArr, float* __restrict__ kkArr, float* __restrict__ bArr,
    const float* __restrict__ aArr, const float* __restrict__ k_k, const float* __restrict__ k_a)
{
  int gid = blockIdx.x * 4 + (threadIdx.x >> 6);
  int lane = threadIdx.x & 63;
  int h = gid & (kH - 1);
  size_t off = (size_t)gid * kN + lane;
  float kv = kArr[off];
  float kkv = kv * k_k[h * kN + lane];
  float ss = kkv * kkv;
  #pragma unroll
  for (int o = 32; o > 0; o >>= 1) ss += __shfl_xor(ss, o);
  float scale = 1.f / fmaxf(sqrtf(ss), 1e-12f);
  float kkf = kkv * scale;
  kkArr[off] = kkf;
  float av = aArr[off];
  bArr[off] = kkf * av;
  kArr[off] = kv * (1.f + (av - 1.f) * k_a[h * kN + lane]);
}

// ---------------- sequential scan: producer/consumer + DPP row reductions ----
// Grid: kH*4 blocks of 320 threads (wave 0 = producer, waves 1-4 consumers).
// Block covers 16 rows of one head. Consumer lane = localRow*16 + col16;
// lane owns s[row][col16*4 .. +3]. All j-reductions via DPP row_ror (VALU,
// no lgkmcnt) across the 16-lane DPP row. Only lgkm ops = 6 prefetch
// ds_reads/step, double-buffered (A/B parity, no register copies).
#define SLOT_F 336   // 5*64 vectors + 16 v
#define NSLOT 24

__device__ __forceinline__ float row_allsum(float x) {
  int t;
  t = __builtin_amdgcn_update_dpp(0, __float_as_int(x), 0x121, 0xF, 0xF, true);  // row_ror:1
  x += __int_as_float(t);
  t = __builtin_amdgcn_update_dpp(0, __float_as_int(x), 0x122, 0xF, 0xF, true);  // row_ror:2
  x += __int_as_float(t);
  t = __builtin_amdgcn_update_dpp(0, __float_as_int(x), 0x124, 0xF, 0xF, true);  // row_ror:4
  x += __int_as_float(t);
  t = __builtin_amdgcn_update_dpp(0, __float_as_int(x), 0x128, 0xF, 0xF, true);  // row_ror:8
  x += __int_as_float(t);
  return x;
}

__global__ __launch_bounds__(320) void scan_kernel(
    const float* __restrict__ s0_in, const float* __restrict__ rA, const float* __restrict__ wA,
    const float* __restrict__ kA, const float* __restrict__ vA, const float* __restrict__ kkA,
    const float* __restrict__ bA, float* __restrict__ y, float* __restrict__ s_out)
{
  __shared__ __align__(16) float ring[NSLOT * SLOT_F];
  int blk = blockIdx.x;
  int h = blk >> 2;
  int i0 = (blk & 3) << 4;        // 16 rows per block
  int wid = threadIdx.x >> 6;
  int lane = threadIdx.x & 63;
  int hv = h * kN;

  if (wid == 0) {
    // -------- producer --------
    const float* src0 = rA + hv;
    const float* src1 = wA + hv;
    const float* src2 = kA + hv;
    const float* src3 = kkA + hv;
    const float* src4 = bA + hv;
    const float* vsrc = vA + hv + i0;
    int slot = 0;
    #define ISSUE(t)                                                                     \
      {                                                                                  \
        float* sb = &ring[slot * SLOT_F];                                                \
        size_t go = (size_t)(t) * kD + lane;                                             \
        __builtin_amdgcn_global_load_lds(                                                \
            (const __attribute__((address_space(1))) uint32*)(src0 + go),                \
            (__attribute__((address_space(3))) uint32*)(sb + 0), 4, 0, 0);               \
        __builtin_amdgcn_global_load_lds(                                                \
            (const __attribute__((address_space(1))) uint32*)(src1 + go),                \
            (__attribute__((address_space(3))) uint32*)(sb + 64), 4, 0, 0);              \
        __builtin_amdgcn_global_load_lds(                                                \
            (const __attribute__((address_space(1))) uint32*)(src2 + go),                \
            (__attribute__((address_space(3))) uint32*)(sb + 128), 4, 0, 0);             \
        __builtin_amdgcn_global_load_lds(                                                \
            (const __attribute__((address_space(1))) uint32*)(src3 + go),                \
            (__attribute__((address_space(3))) uint32*)(sb + 192), 4, 0, 0);             \
        __builtin_amdgcn_global_load_lds(                                                \
            (const __attribute__((address_space(1))) uint32*)(src4 + go),                \
            (__attribute__((address_space(3))) uint32*)(sb + 256), 4, 0, 0);             \
        if (lane < 16)                                                                   \
          __builtin_amdgcn_global_load_lds(                                              \
              (const __attribute__((address_space(1))) uint32*)(vsrc + (size_t)(t) * kD + lane), \
              (__attribute__((address_space(3))) uint32*)(sb + 320), 4, 0, 0);           \
        slot++; if (slot == NSLOT) slot = 0;                                             \
      }
    for (int t = 0; t < 16; t++) ISSUE(t);
    __syncthreads();
    for (int ph = 0; ph < kS / 8; ph++) {
      int t0 = ph * 8 + 16;
      if (t0 < kS) {
        for (int s = 0; s < 8; s++) ISSUE(t0 + s);
      }
      __syncthreads();
    }
    #undef ISSUE
  } else {
    // -------- consumer --------
    int col16 = lane & 15;
    int row = lane >> 4;                 // 0..3 within wave
    int vidx = (wid - 1) * 4 + row;      // 0..15 local row
    int i = i0 + vidx;                   // row within head
    int co = col16 * 4;
    size_t srow = ((size_t)(hv + i)) * kN + co;
    float4 sS = *(const float4*)(s0_in + srow);
    float* py = y + (size_t)(hv + i);

    __syncthreads();   // matches producer prologue barrier

    float4 Ar4, Aw4, Ak4, Akk4, Ab4; float Av1;
    float4 Br4, Bw4, Bk4, Bkk4, Bb4; float Bv1;

    #define LOADSLOT(sl, R, W, K, KK, B, V)                      \
      {                                                          \
        const float* sb = &ring[(sl) * SLOT_F];                  \
        R  = *(const float4*)(sb + co);                          \
        W  = *(const float4*)(sb + 64 + co);                     \
        K  = *(const float4*)(sb + 128 + co);                    \
        KK = *(const float4*)(sb + 192 + co);                    \
        B  = *(const float4*)(sb + 256 + co);                    \
        V  = sb[320 + vidx];                                     \
      }
    #define STEP(R, W, K, KK, B, V)                                       \
      {                                                                   \
        float sa = sS.x * KK.x + sS.y * KK.y + sS.z * KK.z + sS.w * KK.w; \
        sa = row_allsum(sa);                                              \
        sa = -sa;                                                         \
        sS.x = fmaf(sS.x, W.x, fmaf(sa, B.x, V * K.x));                   \
        sS.y = fmaf(sS.y, W.y, fmaf(sa, B.y, V * K.y));                   \
        sS.z = fmaf(sS.z, W.z, fmaf(sa, B.z, V * K.z));                   \
        sS.w = fmaf(sS.w, W.w, fmaf(sa, B.w, V * K.w));                   \
        float yv = sS.x * R.x + sS.y * R.y + sS.z * R.z + sS.w * R.w;     \
        yv = row_allsum(yv);                                              \
        if (col16 == 0) *py = yv;                                         \
        py += kD;                                                         \
      }

    LOADSLOT(0, Ar4, Aw4, Ak4, Akk4, Ab4, Av1);
    int slot = 1;
    for (int ph = 0; ph < kS / 8; ph++) {
      #pragma unroll
      for (int s = 0; s < 8; s += 2) {
        LOADSLOT(slot, Br4, Bw4, Bk4, Bkk4, Bb4, Bv1);
        slot++; if (slot == NSLOT) slot = 0;
        STEP(Ar4, Aw4, Ak4, Akk4, Ab4, Av1);
        LOADSLOT(slot, Ar4, Aw4, Ak4, Akk4, Ab4, Av1);
        slot++; if (slot == NSLOT) slot = 0;
        STEP(Br4, Bw4, Bk4, Bkk4, Bb4, Bv1);
      }
      __syncthreads();
    }
    #undef LOADSLOT
    #undef STEP
    *(float4*)(s_out + srow) = sS;
  }
}

// ---------------- output: groupnorm(y)*lnx + rkv, *gate → bf16 A for Wo -----
__global__ __launch_bounds__(256) void out_kernel(
    const float* __restrict__ y, const float* __restrict__ rA, const float* __restrict__ kA,
    const float* __restrict__ vA, const float* __restrict__ r_k,
    const float* __restrict__ lnw, const float* __restrict__ lnb,
    const float* __restrict__ gate, ushort_t* __restrict__ Ay)
{
  int gid = blockIdx.x * 4 + (threadIdx.x >> 6);
  int lane = threadIdx.x & 63;
  int h = gid & (kH - 1);
  size_t off = (size_t)gid * kN + lane;
  float yv = y[off];
  float s = yv, s2 = yv * yv;
  #pragma unroll
  for (int o = 32; o > 0; o >>= 1) { s += __shfl_xor(s, o); s2 += __shfl_xor(s2, o); }
  float mean = s * (1.f / kN);
  float var = s2 * (1.f / kN) - mean * mean;
  float o1 = (yv - mean) * rsqrtf(var + 0.00064f);
  int d = h * kN + lane;
  float ov = o1 * lnw[d] + lnb[d];
  float p = rA[off] * kA[off] * r_k[d];
  #pragma unroll
  for (int o = 32; o > 0; o >>= 1) p += __shfl_xor(p, o);
  float rkv = p * vA[off];
  Ay[off] = f2bf((ov + rkv) * gate[off]);
}

extern "C" void kernel_launch(void* const* d_in, const int* in_sizes, int n_in,
                              void* d_out, int out_size, void* d_ws, size_t ws_size,
                              hipStream_t stream)
{
  const float* x      = (const float*)d_in[0];
  const float* state1 = (const float*)d_in[1];
  const float* state2 = (const float*)d_in[2];
  const float* vfirst = (const float*)d_in[3];
  const float* ln1w   = (const float*)d_in[4];
  const float* ln1b   = (const float*)d_in[5];
  const float* xr_c   = (const float*)d_in[6];
  const float* xw_c   = (const float*)d_in[7];
  const float* xk_c   = (const float*)d_in[8];
  const float* xv_c   = (const float*)d_in[9];
  const float* xa_c   = (const float*)d_in[10];
  const float* xg_c   = (const float*)d_in[11];
  const float* Wr     = (const float*)d_in[12];
  const float* Wk     = (const float*)d_in[13];
  const float* Wv     = (const float*)d_in[14];
  const float* Wo     = (const float*)d_in[15];
  const float* w1     = (const float*)d_in[16];
  const float* w2     = (const float*)d_in[17];
  const float* w0     = (const float*)d_in[18];
  const float* a1     = (const float*)d_in[19];
  const float* a2     = (const float*)d_in[20];
  const float* a0     = (const float*)d_in[21];
  const float* g1     = (const float*)d_in[22];
  const float* g2     = (const float*)d_in[23];
  const float* v1     = (const float*)d_in[24];
  const float* v2     = (const float*)d_in[25];
  const float* v0     = (const float*)d_in[26];
  const float* k_k    = (const float*)d_in[27];
  const float* k_a    = (const float*)d_in[28];
  const float* r_k    = (const float*)d_in[29];
  const float* lnxw   = (const float*)d_in[30];
  const float* lnxb   = (const float*)d_in[31];

  float* out0  = (float*)d_out;
  float* s1out = out0 + (size_t)kS * kD;
  float* s2out = s1out + kD;

  size_t SD = (size_t)kS * kD;
  float* ws  = (float*)d_ws;
  float* xnB = ws;
  float* rB  = ws + SD;
  float* kB  = ws + 2 * SD;
  float* vB  = ws + 3 * SD;
  float* wB  = ws + 4 * SD;
  float* aB  = ws + 5 * SD;
  float* kkB = ws + 6 * SD;
  float* bB  = ws + 7 * SD;
  float* gB  = ws + 8 * SD;
  float* yB  = ws + 9 * SD;
  // bf16 overlays on temporarily-dead fp32 regions
  ushort_t* ArB = (ushort_t*)kkB;        // dead until post_kernel
  ushort_t* AkB = (ushort_t*)kkB + SD;
  ushort_t* AvB = (ushort_t*)bB;
  ushort_t* WrB = (ushort_t*)yB;         // dead until scan
  ushort_t* WkB = (ushort_t*)yB + SD;
  ushort_t* WvB = (ushort_t*)gB;         // dead until mlp gate write
  ushort_t* AyB = (ushort_t*)aB;         // dead after post_kernel
  ushort_t* WoB = (ushort_t*)rB;         // dead after out_kernel

  ln1_kernel<<<kS, 256, 0, stream>>>(x, ln1w, ln1b, xnB, s1out);
  mix3_cvt<<<kS, 256, 0, stream>>>(xnB, state1, xr_c, xk_c, xv_c, ArB, AkB, AvB);

  const int CVT_BLKS = (int)(SD / 4 / 256);
  {
    CvtArgs ca;
    ca.src[0] = Wr; ca.src[1] = Wk; ca.src[2] = Wv;
    ca.dst[0] = WrB; ca.dst[1] = WkB; ca.dst[2] = WvB;
    cvt_bf16_b<<<dim3(CVT_BLKS, 3), 256, 0, stream>>>(ca);
  }
  {
    GemmArgs ga;
    ga.A[0] = ArB; ga.A[1] = AkB; ga.A[2] = AvB;
    ga.B[0] = WrB; ga.B[1] = WkB; ga.B[2] = WvB;
    ga.C[0] = rB;  ga.C[1] = kB;  ga.C[2] = vB;
    ga.resid[0] = nullptr; ga.resid[1] = nullptr; ga.resid[2] = nullptr;
    gemm_bf16_b<<<dim3(16, 16, 3), 256, 0, stream>>>(ga);
  }

  mlp_kernel<128, 0><<<kS, 256, 0, stream>>>(xnB, state1, xg_c, g1, g2, nullptr, gB, nullptr);
  mlp_kernel<64, 1><<<kS, 256, 0, stream>>>(xnB, state1, xa_c, a1, a2, a0, aB, nullptr);
  mlp_kernel<64, 2><<<kS, 256, 0, stream>>>(xnB, state1, xw_c, w1, w2, w0, wB, nullptr);
  mlp_kernel<32, 3><<<kS, 256, 0, stream>>>(xnB, state1, xv_c, v1, v2, v0, vB, vfirst);

  post_kernel<<<kS * kH / 4, 256, 0, stream>>>(kB, kkB, bB, aB, k_k, k_a);

  scan_kernel<<<kH * 4, 320, 0, stream>>>(state2, rB, wB, kB, vB, kkB, bB, yB, s2out);

  out_kernel<<<kS * kH / 4, 256, 0, stream>>>(yB, rB, kB, vB, r_k, lnxw, lnxb, gB, AyB);

  {
    CvtArgs ca;
    ca.src[0] = Wo; ca.src[1] = Wo; ca.src[2] = Wo;
    ca.dst[0] = WoB; ca.dst[1] = WoB; ca.dst[2] = WoB;
    cvt_bf16_b<<<dim3(CVT_BLKS, 1), 256, 0, stream>>>(ca);
  }
  {
    GemmArgs ga;
    ga.A[0] = AyB; ga.A[1] = AyB; ga.A[2] = AyB;
    ga.B[0] = WoB; ga.B[1] = WoB; ga.B[2] = WoB;
    ga.C[0] = out0; ga.C[1] = out0; ga.C[2] = out0;
    ga.resid[0] = x; ga.resid[1] = x; ga.resid[2] = x;
    gemm_bf16_b<<<dim3(16, 16, 1), 256, 0, stream>>>(ga);
  }
}

// Round 6
// 801.064 us; speedup vs baseline: 3.3800x; 1.3978x over previous
//
#include <hip/hip_runtime.h>
#include <math.h>

#define kD 2048
#define kH 32
#define kN 64
#define kS 2048

typedef unsigned short ushort_t;
typedef unsigned int uint32;

__device__ __forceinline__ ushort_t f2bf(float f) {
  uint32 u = __float_as_uint(f);
  u += 0x7fffu + ((u >> 16) & 1u);   // RNE
  return (ushort_t)(u >> 16);
}
__device__ __forceinline__ float bf2f(ushort_t u) {
  return __uint_as_float(((uint32)u) << 16);
}
__device__ __forceinline__ float sigm(float x) { return 1.f / (1.f + __expf(-x)); }

// ---------------- LayerNorm (ln1): emits bf16 xn and bf16 shifted-xn ---------
__global__ __launch_bounds__(256) void ln1_kernel(
    const float* __restrict__ x, const float* __restrict__ w, const float* __restrict__ b,
    ushort_t* __restrict__ xnbf, ushort_t* __restrict__ xprevbf,
    const float* __restrict__ state1, float* __restrict__ state1_out)
{
  int t = blockIdx.x;
  const float* row = x + (size_t)t * kD;
  float s = 0.f, s2 = 0.f;
  for (int d = threadIdx.x; d < kD; d += 256) {
    float v = row[d]; s += v; s2 += v * v;
  }
  #pragma unroll
  for (int o = 32; o > 0; o >>= 1) { s += __shfl_down(s, o); s2 += __shfl_down(s2, o); }
  __shared__ float ls[4], ls2[4];
  int wid = threadIdx.x >> 6;
  if ((threadIdx.x & 63) == 0) { ls[wid] = s; ls2[wid] = s2; }
  __syncthreads();
  s = ls[0] + ls[1] + ls[2] + ls[3];
  s2 = ls2[0] + ls2[1] + ls2[2] + ls2[3];
  float mean = s * (1.f / kD);
  float var = s2 * (1.f / kD) - mean * mean;
  float rstd = rsqrtf(var + 1e-5f);
  for (int d = threadIdx.x; d < kD; d += 256) {
    float v = (row[d] - mean) * rstd * w[d] + b[d];
    ushort_t bf = f2bf(v);
    xnbf[(size_t)t * kD + d] = bf;
    if (t < kS - 1) xprevbf[(size_t)(t + 1) * kD + d] = bf;
    else state1_out[d] = v;
    if (t == 0) xprevbf[d] = f2bf(state1[d]);
  }
}

// ---------------- mix + bf16 convert for r/k/v GEMM A operands ----------------
__global__ __launch_bounds__(256) void mix3_cvt(
    const ushort_t* __restrict__ xnbf, const ushort_t* __restrict__ xprevbf,
    const float* __restrict__ cr, const float* __restrict__ ck, const float* __restrict__ cv,
    ushort_t* __restrict__ Ar, ushort_t* __restrict__ Ak, ushort_t* __restrict__ Av)
{
  int t = blockIdx.x;
  size_t base = (size_t)t * kD;
  for (int d = threadIdx.x; d < kD; d += 256) {
    float c = bf2f(xnbf[base + d]);
    float dx = bf2f(xprevbf[base + d]) - c;
    Ar[base + d] = f2bf(c + dx * cr[d]);
    Ak[base + d] = f2bf(c + dx * ck[d]);
    Av[base + d] = f2bf(c + dx * cv[d]);
  }
}

// ---------------- batched fp32 -> bf16 ----------------
struct CvtArgs { const float* src[3]; ushort_t* dst[3]; };
__global__ __launch_bounds__(256) void cvt_bf16_b(CvtArgs args)
{
  const float* in = args.src[blockIdx.y];
  ushort_t* out = args.dst[blockIdx.y];
  int idx = blockIdx.x * 256 + threadIdx.x;
  float4 v = ((const float4*)in)[idx];
  ushort_t o[4] = { f2bf(v.x), f2bf(v.y), f2bf(v.z), f2bf(v.w) };
  ((uint2*)out)[idx] = *(const uint2*)o;
}

// ---------------- batched bf16 MFMA NT GEMM (128x128, BK=64) ----------------
typedef __bf16 bf16x8 __attribute__((ext_vector_type(8)));
typedef float f32x4 __attribute__((ext_vector_type(4)));

struct GemmArgs {
  const ushort_t* A[3];
  const ushort_t* B[3];
  float* C[3];
  const float* resid[3];
};

__global__ __launch_bounds__(256) void gemm_bf16_b(GemmArgs args)
{
  int z = blockIdx.z;
  const ushort_t* __restrict__ A = args.A[z];
  const ushort_t* __restrict__ B = args.B[z];
  float* __restrict__ C = args.C[z];
  const float* __restrict__ resid = args.resid[z];

  __shared__ __align__(16) ushort_t As[128 * 64];
  __shared__ __align__(16) ushort_t Bs[128 * 64];
  int tid = threadIdx.x;
  int w = tid >> 6, lane = tid & 63;
  int row0 = blockIdx.y * 128, col0 = blockIdx.x * 128;
  int wrow = (w >> 1) * 64, wcol = (w & 1) * 64;
  int quad = lane >> 4, r16 = lane & 15;
  f32x4 acc[4][4] = {};

  int lrow = lane >> 3;
  int lsw  = (lane & 7) ^ lrow;

  for (int k0 = 0; k0 < kD; k0 += 64) {
    #pragma unroll
    for (int n = 0; n < 4; n++) {
      int rr = w * 32 + n * 8 + lrow;
      int cc = k0 + lsw * 8;
      const ushort_t* ga = A + (size_t)(row0 + rr) * kD + cc;
      const ushort_t* gb = B + (size_t)(col0 + rr) * kD + cc;
      __builtin_amdgcn_global_load_lds(
          (const __attribute__((address_space(1))) uint32*)ga,
          (__attribute__((address_space(3))) uint32*)&As[(w * 32 + n * 8) * 64], 16, 0, 0);
      __builtin_amdgcn_global_load_lds(
          (const __attribute__((address_space(1))) uint32*)gb,
          (__attribute__((address_space(3))) uint32*)&Bs[(w * 32 + n * 8) * 64], 16, 0, 0);
    }
    __syncthreads();
    #pragma unroll
    for (int kk = 0; kk < 64; kk += 32) {
      bf16x8 af[4], bfr[4];
      #pragma unroll
      for (int i = 0; i < 4; i++) {
        int row = wrow + i * 16 + r16;
        int chunk = ((kk >> 3) + quad) ^ (r16 & 7);
        af[i] = *(const bf16x8*)&As[row * 64 + chunk * 8];
      }
      #pragma unroll
      for (int j = 0; j < 4; j++) {
        int row = wcol + j * 16 + r16;
        int chunk = ((kk >> 3) + quad) ^ (r16 & 7);
        bfr[j] = *(const bf16x8*)&Bs[row * 64 + chunk * 8];
      }
      #pragma unroll
      for (int i = 0; i < 4; i++)
        #pragma unroll
        for (int j = 0; j < 4; j++)
          acc[i][j] = __builtin_amdgcn_mfma_f32_16x16x32_bf16(af[i], bfr[j], acc[i][j], 0, 0, 0);
    }
    __syncthreads();
  }
  #pragma unroll
  for (int i = 0; i < 4; i++) {
    #pragma unroll
    for (int j = 0; j < 4; j++) {
      int col = col0 + wcol + j * 16 + r16;
      #pragma unroll
      for (int reg = 0; reg < 4; reg++) {
        int row = row0 + wrow + i * 16 + quad * 4 + reg;
        float v = acc[i][j][reg];
        if (resid) v += resid[(size_t)row * kD + col];
        C[(size_t)row * kD + col] = v;
      }
    }
  }
}

// ---------------- prep W1cat: B1[col][k] (320 x 4096 bf16) -------------------
// col ranges: [0,128)=g1, [128,192)=a1, [192,256)=w1, [256,288)=v1, [288,320)=0
// k<2048: W1[k][lc]*(1-c[k]);  k>=2048: W1[k-2048][lc]*c[k-2048]
struct PrepW1Args { const float* w1[4]; const float* c[4]; ushort_t* B1; };
__global__ __launch_bounds__(256) void prep_w1(PrepW1Args a)
{
  __shared__ float tile[64][17];
  int k0 = blockIdx.x * 64;
  int col0 = blockIdx.y * 16;
  int z, lc0, L;
  if (col0 < 128)      { z = 0; lc0 = col0;       L = 128; }
  else if (col0 < 192) { z = 1; lc0 = col0 - 128; L = 64; }
  else if (col0 < 256) { z = 2; lc0 = col0 - 192; L = 64; }
  else if (col0 < 288) { z = 3; lc0 = col0 - 256; L = 32; }
  else z = -1;
  int tid = threadIdx.x;
  if (z >= 0) {
    const float* W = a.w1[z];
    const float* C = a.c[z];
    int cc = tid & 15, kk = tid >> 4;
    #pragma unroll
    for (int i = 0; i < 4; i++) {
      int k = k0 + kk + i * 16;
      int ksrc = k & (kD - 1);
      float cv = C[ksrc];
      float sc = (k < kD) ? (1.f - cv) : cv;
      tile[kk + i * 16][cc] = W[(size_t)ksrc * L + lc0 + cc] * sc;
    }
  }
  __syncthreads();
  int kk2 = tid & 63, cc2 = tid >> 6;
  #pragma unroll
  for (int i = 0; i < 4; i++) {
    int col = col0 + cc2 * 4 + i;
    float v = (z >= 0) ? tile[kk2][cc2 * 4 + i] : 0.f;
    a.B1[(size_t)col * 4096 + k0 + kk2] = f2bf(v);
  }
}

// ---------------- prep W2: per-z transpose (L x 2048 -> 2048 x L bf16) -------
struct PrepW2Args { const float* w2[4]; ushort_t* B2[4]; int L[4]; };
__global__ __launch_bounds__(256) void prep_w2(PrepW2Args a)
{
  __shared__ float tile[64][17];
  int z = blockIdx.z;
  int L = a.L[z];
  int l0 = blockIdx.y * 16;
  if (l0 >= L) return;
  int j0 = blockIdx.x * 64;
  int tid = threadIdx.x;
  const float* W = a.w2[z];
  ushort_t* out = a.B2[z];
  int jj = tid & 63;
  #pragma unroll
  for (int i = 0; i < 4; i++) {
    int ll = (tid >> 6) * 4 + i;    // 0..15
    tile[jj][ll] = W[(size_t)(l0 + ll) * kD + j0 + jj];
  }
  __syncthreads();
  int ll2 = tid & 15;
  #pragma unroll
  for (int i = 0; i < 4; i++) {
    int jj2 = (tid >> 4) + i * 16;  // 0..63
    out[(size_t)(j0 + jj2) * L + l0 + ll2] = f2bf(tile[jj2][ll2]);
  }
}

// ---------------- GEMM1: H = [xn | xprev] @ B1cat^T  (2048 x 4096 x 320) -----
// block: 128 rows x 64 cols, 4 waves stacked on rows. Epilogue activation by
// column range, writes bf16 H (row stride 320).
__global__ __launch_bounds__(256) void gemm1_kernel(
    const ushort_t* __restrict__ xnbf, const ushort_t* __restrict__ xprevbf,
    const ushort_t* __restrict__ B1, ushort_t* __restrict__ H)
{
  __shared__ __align__(16) ushort_t As[128 * 64];
  __shared__ __align__(16) ushort_t Bs[64 * 64];
  int tid = threadIdx.x;
  int w = tid >> 6, lane = tid & 63;
  int col0 = blockIdx.x * 64, row0 = blockIdx.y * 128;
  int quad = lane >> 4, r16 = lane & 15;
  f32x4 acc[2][4] = {};
  int lrow = lane >> 3;
  int lsw = (lane & 7) ^ lrow;

  for (int k0 = 0; k0 < 4096; k0 += 64) {
    const ushort_t* Abase = (k0 < kD) ? (xnbf + k0) : (xprevbf + (k0 - kD));
    #pragma unroll
    for (int n = 0; n < 4; n++) {
      int rr = w * 32 + n * 8 + lrow;
      const ushort_t* ga = Abase + (size_t)(row0 + rr) * kD + lsw * 8;
      __builtin_amdgcn_global_load_lds(
          (const __attribute__((address_space(1))) uint32*)ga,
          (__attribute__((address_space(3))) uint32*)&As[(w * 32 + n * 8) * 64], 16, 0, 0);
    }
    #pragma unroll
    for (int n = 0; n < 2; n++) {
      int rr = w * 16 + n * 8 + lrow;
      const ushort_t* gb = B1 + (size_t)(col0 + rr) * 4096 + k0 + lsw * 8;
      __builtin_amdgcn_global_load_lds(
          (const __attribute__((address_space(1))) uint32*)gb,
          (__attribute__((address_space(3))) uint32*)&Bs[(w * 16 + n * 8) * 64], 16, 0, 0);
    }
    __syncthreads();
    #pragma unroll
    for (int kk = 0; kk < 64; kk += 32) {
      bf16x8 af[2], bfr[4];
      #pragma unroll
      for (int i = 0; i < 2; i++) {
        int row = w * 32 + i * 16 + r16;
        int chunk = ((kk >> 3) + quad) ^ (r16 & 7);
        af[i] = *(const bf16x8*)&As[row * 64 + chunk * 8];
      }
      #pragma unroll
      for (int j = 0; j < 4; j++) {
        int row = j * 16 + r16;
        int chunk = ((kk >> 3) + quad) ^ (r16 & 7);
        bfr[j] = *(const bf16x8*)&Bs[row * 64 + chunk * 8];
      }
      #pragma unroll
      for (int i = 0; i < 2; i++)
        #pragma unroll
        for (int j = 0; j < 4; j++)
          acc[i][j] = __builtin_amdgcn_mfma_f32_16x16x32_bf16(af[i], bfr[j], acc[i][j], 0, 0, 0);
    }
    __syncthreads();
  }
  #pragma unroll
  for (int i = 0; i < 2; i++) {
    #pragma unroll
    for (int j = 0; j < 4; j++) {
      int col = col0 + j * 16 + r16;
      #pragma unroll
      for (int reg = 0; reg < 4; reg++) {
        int row = row0 + w * 32 + i * 16 + quad * 4 + reg;
        float v = acc[i][j][reg];
        if (col < 128) v = sigm(v);
        else if (col >= 192 && col < 256) v = tanhf(v);
        H[(size_t)row * 320 + col] = f2bf(v);
      }
    }
  }
}

// ---------------- GEMM2 (z-batched, K=Lz): out = act(H_z @ W2_z + bias) ------
struct Gemm2Args {
  const ushort_t* H;
  const ushort_t* B2[4];
  int Aofs[4];
  int L[4];
  const float* bias[4];
  float* out[4];
  const float* vfirst;
};
__global__ __launch_bounds__(256) void gemm2_kernel(Gemm2Args a)
{
  int z = blockIdx.z;
  int L = a.L[z];
  int nch = L >> 3;
  int rs = __builtin_ctz(nch);
  int mask = (nch >= 8) ? 7 : (nch - 1);
  __shared__ __align__(16) ushort_t As[128 * 128];
  __shared__ __align__(16) ushort_t Bs[128 * 128];
  int tid = threadIdx.x;
  int w = tid >> 6, lane = tid & 63;
  int row0 = blockIdx.y * 128, col0 = blockIdx.x * 128;
  int wrow = (w >> 1) * 64, wcol = (w & 1) * 64;
  int quad = lane >> 4, r16 = lane & 15;
  const ushort_t* A = a.H + a.Aofs[z];
  const ushort_t* B = a.B2[z];

  int nld = (128 * nch) >> 8;
  for (int i = 0; i < nld; i++) {
    int c = i * 256 + w * 64 + lane;
    int row = c >> rs;
    int ch = c & (nch - 1);
    int gch = ch ^ (row & mask);
    __builtin_amdgcn_global_load_lds(
        (const __attribute__((address_space(1))) uint32*)(A + (size_t)(row0 + row) * 320 + gch * 8),
        (__attribute__((address_space(3))) uint32*)&As[(i * 256 + w * 64) * 8], 16, 0, 0);
    __builtin_amdgcn_global_load_lds(
        (const __attribute__((address_space(1))) uint32*)(B + (size_t)(col0 + row) * L + gch * 8),
        (__attribute__((address_space(3))) uint32*)&Bs[(i * 256 + w * 64) * 8], 16, 0, 0);
  }
  __syncthreads();

  f32x4 acc[4][4] = {};
  int ksteps = L >> 5;
  for (int ks = 0; ks < ksteps; ks++) {
    bf16x8 af[4], bfr[4];
    #pragma unroll
    for (int i = 0; i < 4; i++) {
      int row = wrow + i * 16 + r16;
      int slot = ((ks << 2) + quad) ^ (r16 & mask);
      af[i] = *(const bf16x8*)&As[row * L + slot * 8];
    }
    #pragma unroll
    for (int j = 0; j < 4; j++) {
      int row = wcol + j * 16 + r16;
      int slot = ((ks << 2) + quad) ^ (r16 & mask);
      bfr[j] = *(const bf16x8*)&Bs[row * L + slot * 8];
    }
    #pragma unroll
    for (int i = 0; i < 4; i++)
      #pragma unroll
      for (int j = 0; j < 4; j++)
        acc[i][j] = __builtin_amdgcn_mfma_f32_16x16x32_bf16(af[i], bfr[j], acc[i][j], 0, 0, 0);
  }

  const float* bias = a.bias[z];
  float* C = a.out[z];
  #pragma unroll
  for (int i = 0; i < 4; i++) {
    #pragma unroll
    for (int j = 0; j < 4; j++) {
      int col = col0 + wcol + j * 16 + r16;
      #pragma unroll
      for (int reg = 0; reg < 4; reg++) {
        int row = row0 + wrow + i * 16 + quad * 4 + reg;
        float s = acc[i][j][reg];
        size_t idx = (size_t)row * kD + col;
        if (z == 0) {
          C[idx] = s;
        } else if (z == 1) {
          C[idx] = sigm(s + bias[col]);
        } else if (z == 2) {
          C[idx] = __expf(-0.606531f * sigm(s + bias[col]));
        } else {
          float vv = C[idx];
          C[idx] = vv + (a.vfirst[idx] - vv) * sigm(s + bias[col]);
        }
      }
    }
  }
}

// ---------------- post: kk (normalized), k update, b ----------------
__global__ __launch_bounds__(256) void post_kernel(
    float* __restrict__ kArr, float* __restrict__ kkArr, float* __restrict__ bArr,
    const float* __restrict__ aArr, const float* __restrict__ k_k, const float* __restrict__ k_a)
{
  int gid = blockIdx.x * 4 + (threadIdx.x >> 6);
  int lane = threadIdx.x & 63;
  int h = gid & (kH - 1);
  size_t off = (size_t)gid * kN + lane;
  float kv = kArr[off];
  float kkv = kv * k_k[h * kN + lane];
  float ss = kkv * kkv;
  #pragma unroll
  for (int o = 32; o > 0; o >>= 1) ss += __shfl_xor(ss, o);
  float scale = 1.f / fmaxf(sqrtf(ss), 1e-12f);
  float kkf = kkv * scale;
  kkArr[off] = kkf;
  float av = aArr[off];
  bArr[off] = kkf * av;
  kArr[off] = kv * (1.f + (av - 1.f) * k_a[h * kN + lane]);
}

// ---------------- sequential scan: producer/consumer + DPP row reductions ----
#define SLOT_F 336
#define NSLOT 24

__device__ __forceinline__ float row_allsum(float x) {
  int t;
  t = __builtin_amdgcn_update_dpp(0, __float_as_int(x), 0x121, 0xF, 0xF, true);
  x += __int_as_float(t);
  t = __builtin_amdgcn_update_dpp(0, __float_as_int(x), 0x122, 0xF, 0xF, true);
  x += __int_as_float(t);
  t = __builtin_amdgcn_update_dpp(0, __float_as_int(x), 0x124, 0xF, 0xF, true);
  x += __int_as_float(t);
  t = __builtin_amdgcn_update_dpp(0, __float_as_int(x), 0x128, 0xF, 0xF, true);
  x += __int_as_float(t);
  return x;
}

__global__ __launch_bounds__(320) void scan_kernel(
    const float* __restrict__ s0_in, const float* __restrict__ rA, const float* __restrict__ wA,
    const float* __restrict__ kA, const float* __restrict__ vA, const float* __restrict__ kkA,
    const float* __restrict__ bA, float* __restrict__ y, float* __restrict__ s_out)
{
  __shared__ __align__(16) float ring[NSLOT * SLOT_F];
  int blk = blockIdx.x;
  int h = blk >> 2;
  int i0 = (blk & 3) << 4;
  int wid = threadIdx.x >> 6;
  int lane = threadIdx.x & 63;
  int hv = h * kN;

  if (wid == 0) {
    const float* src0 = rA + hv;
    const float* src1 = wA + hv;
    const float* src2 = kA + hv;
    const float* src3 = kkA + hv;
    const float* src4 = bA + hv;
    const float* vsrc = vA + hv + i0;
    int slot = 0;
    #define ISSUE(t)                                                                     \
      {                                                                                  \
        float* sb = &ring[slot * SLOT_F];                                                \
        size_t go = (size_t)(t) * kD + lane;                                             \
        __builtin_amdgcn_global_load_lds(                                                \
            (const __attribute__((address_space(1))) uint32*)(src0 + go),                \
            (__attribute__((address_space(3))) uint32*)(sb + 0), 4, 0, 0);               \
        __builtin_amdgcn_global_load_lds(                                                \
            (const __attribute__((address_space(1))) uint32*)(src1 + go),                \
            (__attribute__((address_space(3))) uint32*)(sb + 64), 4, 0, 0);              \
        __builtin_amdgcn_global_load_lds(                                                \
            (const __attribute__((address_space(1))) uint32*)(src2 + go),                \
            (__attribute__((address_space(3))) uint32*)(sb + 128), 4, 0, 0);             \
        __builtin_amdgcn_global_load_lds(                                                \
            (const __attribute__((address_space(1))) uint32*)(src3 + go),                \
            (__attribute__((address_space(3))) uint32*)(sb + 192), 4, 0, 0);             \
        __builtin_amdgcn_global_load_lds(                                                \
            (const __attribute__((address_space(1))) uint32*)(src4 + go),                \
            (__attribute__((address_space(3))) uint32*)(sb + 256), 4, 0, 0);             \
        if (lane < 16)                                                                   \
          __builtin_amdgcn_global_load_lds(                                              \
              (const __attribute__((address_space(1))) uint32*)(vsrc + (size_t)(t) * kD + lane), \
              (__attribute__((address_space(3))) uint32*)(sb + 320), 4, 0, 0);           \
        slot++; if (slot == NSLOT) slot = 0;                                             \
      }
    for (int t = 0; t < 16; t++) ISSUE(t);
    __syncthreads();
    for (int ph = 0; ph < kS / 8; ph++) {
      int t0 = ph * 8 + 16;
      if (t0 < kS) {
        for (int s = 0; s < 8; s++) ISSUE(t0 + s);
      }
      __syncthreads();
    }
    #undef ISSUE
  } else {
    int col16 = lane & 15;
    int row = lane >> 4;
    int vidx = (wid - 1) * 4 + row;
    int i = i0 + vidx;
    int co = col16 * 4;
    size_t srow = ((size_t)(hv + i)) * kN + co;
    float4 sS = *(const float4*)(s0_in + srow);
    float* py = y + (size_t)(hv + i);

    __syncthreads();

    float4 Ar4, Aw4, Ak4, Akk4, Ab4; float Av1;
    float4 Br4, Bw4, Bk4, Bkk4, Bb4; float Bv1;

    #define LOADSLOT(sl, R, W, K, KK, B, V)                      \
      {                                                          \
        const float* sb = &ring[(sl) * SLOT_F];                  \
        R  = *(const float4*)(sb + co);                          \
        W  = *(const float4*)(sb + 64 + co);                     \
        K  = *(const float4*)(sb + 128 + co);                    \
        KK = *(const float4*)(sb + 192 + co);                    \
        B  = *(const float4*)(sb + 256 + co);                    \
        V  = sb[320 + vidx];                                     \
      }
    #define STEP(R, W, K, KK, B, V)                                       \
      {                                                                   \
        float sa = sS.x * KK.x + sS.y * KK.y + sS.z * KK.z + sS.w * KK.w; \
        sa = row_allsum(sa);                                              \
        sa = -sa;                                                         \
        sS.x = fmaf(sS.x, W.x, fmaf(sa, B.x, V * K.x));                   \
        sS.y = fmaf(sS.y, W.y, fmaf(sa, B.y, V * K.y));                   \
        sS.z = fmaf(sS.z, W.z, fmaf(sa, B.z, V * K.z));                   \
        sS.w = fmaf(sS.w, W.w, fmaf(sa, B.w, V * K.w));                   \
        float yv = sS.x * R.x + sS.y * R.y + sS.z * R.z + sS.w * R.w;     \
        yv = row_allsum(yv);                                              \
        if (col16 == 0) *py = yv;                                         \
        py += kD;                                                         \
      }

    LOADSLOT(0, Ar4, Aw4, Ak4, Akk4, Ab4, Av1);
    int slot = 1;
    for (int ph = 0; ph < kS / 8; ph++) {
      #pragma unroll
      for (int s = 0; s < 8; s += 2) {
        LOADSLOT(slot, Br4, Bw4, Bk4, Bkk4, Bb4, Bv1);
        slot++; if (slot == NSLOT) slot = 0;
        STEP(Ar4, Aw4, Ak4, Akk4, Ab4, Av1);
        LOADSLOT(slot, Ar4, Aw4, Ak4, Akk4, Ab4, Av1);
        slot++; if (slot == NSLOT) slot = 0;
        STEP(Br4, Bw4, Bk4, Bkk4, Bb4, Bv1);
      }
      __syncthreads();
    }
    #undef LOADSLOT
    #undef STEP
    *(float4*)(s_out + srow) = sS;
  }
}

// ---------------- output: groupnorm(y)*lnx + rkv, *gate → bf16 A for Wo -----
__global__ __launch_bounds__(256) void out_kernel(
    const float* __restrict__ y, const float* __restrict__ rA, const float* __restrict__ kA,
    const float* __restrict__ vA, const float* __restrict__ r_k,
    const float* __restrict__ lnw, const float* __restrict__ lnb,
    const float* __restrict__ gate, ushort_t* __restrict__ Ay)
{
  int gid = blockIdx.x * 4 + (threadIdx.x >> 6);
  int lane = threadIdx.x & 63;
  int h = gid & (kH - 1);
  size_t off = (size_t)gid * kN + lane;
  float yv = y[off];
  float s = yv, s2 = yv * yv;
  #pragma unroll
  for (int o = 32; o > 0; o >>= 1) { s += __shfl_xor(s, o); s2 += __shfl_xor(s2, o); }
  float mean = s * (1.f / kN);
  float var = s2 * (1.f / kN) - mean * mean;
  float o1 = (yv - mean) * rsqrtf(var + 0.00064f);
  int d = h * kN + lane;
  float ov = o1 * lnw[d] + lnb[d];
  float p = rA[off] * kA[off] * r_k[d];
  #pragma unroll
  for (int o = 32; o > 0; o >>= 1) p += __shfl_xor(p, o);
  float rkv = p * vA[off];
  Ay[off] = f2bf((ov + rkv) * gate[off]);
}

extern "C" void kernel_launch(void* const* d_in, const int* in_sizes, int n_in,
                              void* d_out, int out_size, void* d_ws, size_t ws_size,
                              hipStream_t stream)
{
  const float* x      = (const float*)d_in[0];
  const float* state1 = (const float*)d_in[1];
  const float* state2 = (const float*)d_in[2];
  const float* vfirst = (const float*)d_in[3];
  const float* ln1w   = (const float*)d_in[4];
  const float* ln1b   = (const float*)d_in[5];
  const float* xr_c   = (const float*)d_in[6];
  const float* xw_c   = (const float*)d_in[7];
  const float* xk_c   = (const float*)d_in[8];
  const float* xv_c   = (const float*)d_in[9];
  const float* xa_c   = (const float*)d_in[10];
  const float* xg_c   = (const float*)d_in[11];
  const float* Wr     = (const float*)d_in[12];
  const float* Wk     = (const float*)d_in[13];
  const float* Wv     = (const float*)d_in[14];
  const float* Wo     = (const float*)d_in[15];
  const float* w1     = (const float*)d_in[16];
  const float* w2     = (const float*)d_in[17];
  const float* w0     = (const float*)d_in[18];
  const float* a1     = (const float*)d_in[19];
  const float* a2     = (const float*)d_in[20];
  const float* a0     = (const float*)d_in[21];
  const float* g1     = (const float*)d_in[22];
  const float* g2     = (const float*)d_in[23];
  const float* v1     = (const float*)d_in[24];
  const float* v2     = (const float*)d_in[25];
  const float* v0     = (const float*)d_in[26];
  const float* k_k    = (const float*)d_in[27];
  const float* k_a    = (const float*)d_in[28];
  const float* r_k    = (const float*)d_in[29];
  const float* lnxw   = (const float*)d_in[30];
  const float* lnxb   = (const float*)d_in[31];

  float* out0  = (float*)d_out;
  float* s1out = out0 + (size_t)kS * kD;
  float* s2out = s1out + kD;

  size_t SD = (size_t)kS * kD;
  float* ws  = (float*)d_ws;
  float* xnB = ws;                 // bf16 xn + bf16 xprev
  float* rB  = ws + SD;
  float* kB  = ws + 2 * SD;
  float* vB  = ws + 3 * SD;
  float* wB  = ws + 4 * SD;
  float* aB  = ws + 5 * SD;
  float* kkB = ws + 6 * SD;
  float* bB  = ws + 7 * SD;
  float* gB  = ws + 8 * SD;
  float* yB  = ws + 9 * SD;

  ushort_t* xnbf    = (ushort_t*)xnB;
  ushort_t* xprevbf = (ushort_t*)xnB + SD;
  ushort_t* ArB = (ushort_t*)kkB;        // dead before post writes kkB
  ushort_t* AkB = (ushort_t*)kkB + SD;
  ushort_t* AvB = (ushort_t*)bB;         // bB first half
  ushort_t* B1  = (ushort_t*)bB + SD;    // bB second half: B1 | H | B2
  ushort_t* Hbuf = B1 + (size_t)320 * 4096;
  ushort_t* B2g  = Hbuf + (size_t)2048 * 320;
  ushort_t* B2a  = B2g + (size_t)2048 * 128;
  ushort_t* B2w  = B2a + (size_t)2048 * 64;
  ushort_t* B2v  = B2w + (size_t)2048 * 64;
  ushort_t* WrB = (ushort_t*)yB;         // dead before scan writes yB
  ushort_t* WkB = (ushort_t*)yB + SD;
  ushort_t* WvB = (ushort_t*)gB;         // dead before gemm2 writes gB
  ushort_t* AyB = (ushort_t*)aB;         // aB dead after post
  ushort_t* WoB = (ushort_t*)rB;         // rB dead after out_kernel

  ln1_kernel<<<kS, 256, 0, stream>>>(x, ln1w, ln1b, xnbf, xprevbf, state1, s1out);
  mix3_cvt<<<kS, 256, 0, stream>>>(xnbf, xprevbf, xr_c, xk_c, xv_c, ArB, AkB, AvB);

  const int CVT_BLKS = (int)(SD / 4 / 256);
  {
    CvtArgs ca;
    ca.src[0] = Wr; ca.src[1] = Wk; ca.src[2] = Wv;
    ca.dst[0] = WrB; ca.dst[1] = WkB; ca.dst[2] = WvB;
    cvt_bf16_b<<<dim3(CVT_BLKS, 3), 256, 0, stream>>>(ca);
  }
  {
    PrepW1Args pa;
    pa.w1[0] = g1; pa.w1[1] = a1; pa.w1[2] = w1; pa.w1[3] = v1;
    pa.c[0] = xg_c; pa.c[1] = xa_c; pa.c[2] = xw_c; pa.c[3] = xv_c;
    pa.B1 = B1;
    prep_w1<<<dim3(64, 20), 256, 0, stream>>>(pa);
  }
  {
    PrepW2Args pa;
    pa.w2[0] = g2; pa.w2[1] = a2; pa.w2[2] = w2; pa.w2[3] = v2;
    pa.B2[0] = B2g; pa.B2[1] = B2a; pa.B2[2] = B2w; pa.B2[3] = B2v;
    pa.L[0] = 128; pa.L[1] = 64; pa.L[2] = 64; pa.L[3] = 32;
    prep_w2<<<dim3(32, 8, 4), 256, 0, stream>>>(pa);
  }
  {
    GemmArgs ga;
    ga.A[0] = ArB; ga.A[1] = AkB; ga.A[2] = AvB;
    ga.B[0] = WrB; ga.B[1] = WkB; ga.B[2] = WvB;
    ga.C[0] = rB;  ga.C[1] = kB;  ga.C[2] = vB;
    ga.resid[0] = nullptr; ga.resid[1] = nullptr; ga.resid[2] = nullptr;
    gemm_bf16_b<<<dim3(16, 16, 3), 256, 0, stream>>>(ga);
  }

  gemm1_kernel<<<dim3(5, 16), 256, 0, stream>>>(xnbf, xprevbf, B1, Hbuf);
  {
    Gemm2Args ga;
    ga.H = Hbuf;
    ga.B2[0] = B2g; ga.B2[1] = B2a; ga.B2[2] = B2w; ga.B2[3] = B2v;
    ga.Aofs[0] = 0; ga.Aofs[1] = 128; ga.Aofs[2] = 192; ga.Aofs[3] = 256;
    ga.L[0] = 128; ga.L[1] = 64; ga.L[2] = 64; ga.L[3] = 32;
    ga.bias[0] = nullptr; ga.bias[1] = a0; ga.bias[2] = w0; ga.bias[3] = v0;
    ga.out[0] = gB; ga.out[1] = aB; ga.out[2] = wB; ga.out[3] = vB;
    ga.vfirst = vfirst;
    gemm2_kernel<<<dim3(16, 16, 4), 256, 0, stream>>>(ga);
  }

  post_kernel<<<kS * kH / 4, 256, 0, stream>>>(kB, kkB, bB, aB, k_k, k_a);

  scan_kernel<<<kH * 4, 320, 0, stream>>>(state2, rB, wB, kB, vB, kkB, bB, yB, s2out);

  out_kernel<<<kS * kH / 4, 256, 0, stream>>>(yB, rB, kB, vB, r_k, lnxw, lnxb, gB, AyB);

  {
    CvtArgs ca;
    ca.src[0] = Wo; ca.src[1] = Wo; ca.src[2] = Wo;
    ca.dst[0] = WoB; ca.dst[1] = WoB; ca.dst[2] = WoB;
    cvt_bf16_b<<<dim3(CVT_BLKS, 1), 256, 0, stream>>>(ca);
  }
  {
    GemmArgs ga;
    ga.A[0] = AyB; ga.A[1] = AyB; ga.A[2] = AyB;
    ga.B[0] = WoB; ga.B[1] = WoB; ga.B[2] = WoB;
    ga.C[0] = out0; ga.C[1] = out0; ga.C[2] = out0;
    ga.resid[0] = x; ga.resid[1] = x; ga.resid[2] = x;
    gemm_bf16_b<<<dim3(16, 16, 1), 256, 0, stream>>>(ga);
  }
}

// Round 7
// 770.035 us; speedup vs baseline: 3.5162x; 1.0403x over previous
//
#include <hip/hip_runtime.h>
#include <math.h>

#define kD 2048
#define kH 32
#define kN 64
#define kS 2048

typedef unsigned short ushort_t;
typedef unsigned int uint32;

__device__ __forceinline__ ushort_t f2bf(float f) {
  uint32 u = __float_as_uint(f);
  u += 0x7fffu + ((u >> 16) & 1u);   // RNE
  return (ushort_t)(u >> 16);
}
__device__ __forceinline__ float bf2f(ushort_t u) {
  return __uint_as_float(((uint32)u) << 16);
}
__device__ __forceinline__ float sigm(float x) { return 1.f / (1.f + __expf(-x)); }

// ---------------- LayerNorm (ln1): emits bf16 xn and bf16 shifted-xn ---------
__global__ __launch_bounds__(256) void ln1_kernel(
    const float* __restrict__ x, const float* __restrict__ w, const float* __restrict__ b,
    ushort_t* __restrict__ xnbf, ushort_t* __restrict__ xprevbf,
    const float* __restrict__ state1, float* __restrict__ state1_out)
{
  int t = blockIdx.x;
  const float* row = x + (size_t)t * kD;
  float s = 0.f, s2 = 0.f;
  for (int d = threadIdx.x; d < kD; d += 256) {
    float v = row[d]; s += v; s2 += v * v;
  }
  #pragma unroll
  for (int o = 32; o > 0; o >>= 1) { s += __shfl_down(s, o); s2 += __shfl_down(s2, o); }
  __shared__ float ls[4], ls2[4];
  int wid = threadIdx.x >> 6;
  if ((threadIdx.x & 63) == 0) { ls[wid] = s; ls2[wid] = s2; }
  __syncthreads();
  s = ls[0] + ls[1] + ls[2] + ls[3];
  s2 = ls2[0] + ls2[1] + ls2[2] + ls2[3];
  float mean = s * (1.f / kD);
  float var = s2 * (1.f / kD) - mean * mean;
  float rstd = rsqrtf(var + 1e-5f);
  for (int d = threadIdx.x; d < kD; d += 256) {
    float v = (row[d] - mean) * rstd * w[d] + b[d];
    ushort_t bf = f2bf(v);
    xnbf[(size_t)t * kD + d] = bf;
    if (t < kS - 1) xprevbf[(size_t)(t + 1) * kD + d] = bf;
    else state1_out[d] = v;
    if (t == 0) xprevbf[d] = f2bf(state1[d]);
  }
}

// ---------------- mix + bf16 convert for r/k/v GEMM A operands ----------------
__global__ __launch_bounds__(256) void mix3_cvt(
    const ushort_t* __restrict__ xnbf, const ushort_t* __restrict__ xprevbf,
    const float* __restrict__ cr, const float* __restrict__ ck, const float* __restrict__ cv,
    ushort_t* __restrict__ Ar, ushort_t* __restrict__ Ak, ushort_t* __restrict__ Av)
{
  int t = blockIdx.x;
  size_t base = (size_t)t * kD;
  for (int d = threadIdx.x; d < kD; d += 256) {
    float c = bf2f(xnbf[base + d]);
    float dx = bf2f(xprevbf[base + d]) - c;
    Ar[base + d] = f2bf(c + dx * cr[d]);
    Ak[base + d] = f2bf(c + dx * ck[d]);
    Av[base + d] = f2bf(c + dx * cv[d]);
  }
}

// ---------------- batched fp32 -> bf16 ----------------
struct CvtArgs { const float* src[3]; ushort_t* dst[3]; };
__global__ __launch_bounds__(256) void cvt_bf16_b(CvtArgs args)
{
  const float* in = args.src[blockIdx.y];
  ushort_t* out = args.dst[blockIdx.y];
  int idx = blockIdx.x * 256 + threadIdx.x;
  float4 v = ((const float4*)in)[idx];
  ushort_t o[4] = { f2bf(v.x), f2bf(v.y), f2bf(v.z), f2bf(v.w) };
  ((uint2*)out)[idx] = *(const uint2*)o;
}

// ---------------- batched bf16 MFMA NT GEMM (128x128, BK=64) ----------------
typedef __bf16 bf16x8 __attribute__((ext_vector_type(8)));
typedef float f32x4 __attribute__((ext_vector_type(4)));

struct GemmArgs {
  const ushort_t* A[3];
  const ushort_t* B[3];
  float* C[3];
  const float* resid[3];
};

__global__ __launch_bounds__(256) void gemm_bf16_b(GemmArgs args)
{
  int z = blockIdx.z;
  const ushort_t* __restrict__ A = args.A[z];
  const ushort_t* __restrict__ B = args.B[z];
  float* __restrict__ C = args.C[z];
  const float* __restrict__ resid = args.resid[z];

  __shared__ __align__(16) ushort_t As[128 * 64];
  __shared__ __align__(16) ushort_t Bs[128 * 64];
  int tid = threadIdx.x;
  int w = tid >> 6, lane = tid & 63;
  int row0 = blockIdx.y * 128, col0 = blockIdx.x * 128;
  int wrow = (w >> 1) * 64, wcol = (w & 1) * 64;
  int quad = lane >> 4, r16 = lane & 15;
  f32x4 acc[4][4] = {};

  int lrow = lane >> 3;
  int lsw  = (lane & 7) ^ lrow;

  for (int k0 = 0; k0 < kD; k0 += 64) {
    #pragma unroll
    for (int n = 0; n < 4; n++) {
      int rr = w * 32 + n * 8 + lrow;
      int cc = k0 + lsw * 8;
      const ushort_t* ga = A + (size_t)(row0 + rr) * kD + cc;
      const ushort_t* gb = B + (size_t)(col0 + rr) * kD + cc;
      __builtin_amdgcn_global_load_lds(
          (const __attribute__((address_space(1))) uint32*)ga,
          (__attribute__((address_space(3))) uint32*)&As[(w * 32 + n * 8) * 64], 16, 0, 0);
      __builtin_amdgcn_global_load_lds(
          (const __attribute__((address_space(1))) uint32*)gb,
          (__attribute__((address_space(3))) uint32*)&Bs[(w * 32 + n * 8) * 64], 16, 0, 0);
    }
    __syncthreads();
    #pragma unroll
    for (int kk = 0; kk < 64; kk += 32) {
      bf16x8 af[4], bfr[4];
      #pragma unroll
      for (int i = 0; i < 4; i++) {
        int row = wrow + i * 16 + r16;
        int chunk = ((kk >> 3) + quad) ^ (r16 & 7);
        af[i] = *(const bf16x8*)&As[row * 64 + chunk * 8];
      }
      #pragma unroll
      for (int j = 0; j < 4; j++) {
        int row = wcol + j * 16 + r16;
        int chunk = ((kk >> 3) + quad) ^ (r16 & 7);
        bfr[j] = *(const bf16x8*)&Bs[row * 64 + chunk * 8];
      }
      #pragma unroll
      for (int i = 0; i < 4; i++)
        #pragma unroll
        for (int j = 0; j < 4; j++)
          acc[i][j] = __builtin_amdgcn_mfma_f32_16x16x32_bf16(af[i], bfr[j], acc[i][j], 0, 0, 0);
    }
    __syncthreads();
  }
  #pragma unroll
  for (int i = 0; i < 4; i++) {
    #pragma unroll
    for (int j = 0; j < 4; j++) {
      int col = col0 + wcol + j * 16 + r16;
      #pragma unroll
      for (int reg = 0; reg < 4; reg++) {
        int row = row0 + wrow + i * 16 + quad * 4 + reg;
        float v = acc[i][j][reg];
        if (resid) v += resid[(size_t)row * kD + col];
        C[(size_t)row * kD + col] = v;
      }
    }
  }
}

// ---------------- prep W1cat: B1[col][k] (320 x 4096 bf16) -------------------
struct PrepW1Args { const float* w1[4]; const float* c[4]; ushort_t* B1; };
__global__ __launch_bounds__(256) void prep_w1(PrepW1Args a)
{
  __shared__ float tile[64][17];
  int k0 = blockIdx.x * 64;
  int col0 = blockIdx.y * 16;
  int z, lc0, L;
  if (col0 < 128)      { z = 0; lc0 = col0;       L = 128; }
  else if (col0 < 192) { z = 1; lc0 = col0 - 128; L = 64; }
  else if (col0 < 256) { z = 2; lc0 = col0 - 192; L = 64; }
  else if (col0 < 288) { z = 3; lc0 = col0 - 256; L = 32; }
  else z = -1;
  int tid = threadIdx.x;
  if (z >= 0) {
    const float* W = a.w1[z];
    const float* C = a.c[z];
    int cc = tid & 15, kk = tid >> 4;
    #pragma unroll
    for (int i = 0; i < 4; i++) {
      int k = k0 + kk + i * 16;
      int ksrc = k & (kD - 1);
      float cv = C[ksrc];
      float sc = (k < kD) ? (1.f - cv) : cv;
      tile[kk + i * 16][cc] = W[(size_t)ksrc * L + lc0 + cc] * sc;
    }
  }
  __syncthreads();
  int kk2 = tid & 63, cc2 = tid >> 6;
  #pragma unroll
  for (int i = 0; i < 4; i++) {
    int col = col0 + cc2 * 4 + i;
    float v = (z >= 0) ? tile[kk2][cc2 * 4 + i] : 0.f;
    a.B1[(size_t)col * 4096 + k0 + kk2] = f2bf(v);
  }
}

// ---------------- prep W2: per-z transpose (L x 2048 -> 2048 x L bf16) -------
struct PrepW2Args { const float* w2[4]; ushort_t* B2[4]; int L[4]; };
__global__ __launch_bounds__(256) void prep_w2(PrepW2Args a)
{
  __shared__ float tile[64][17];
  int z = blockIdx.z;
  int L = a.L[z];
  int l0 = blockIdx.y * 16;
  if (l0 >= L) return;
  int j0 = blockIdx.x * 64;
  int tid = threadIdx.x;
  const float* W = a.w2[z];
  ushort_t* out = a.B2[z];
  int jj = tid & 63;
  #pragma unroll
  for (int i = 0; i < 4; i++) {
    int ll = (tid >> 6) * 4 + i;
    tile[jj][ll] = W[(size_t)(l0 + ll) * kD + j0 + jj];
  }
  __syncthreads();
  int ll2 = tid & 15;
  #pragma unroll
  for (int i = 0; i < 4; i++) {
    int jj2 = (tid >> 4) + i * 16;
    out[(size_t)(j0 + jj2) * L + l0 + ll2] = f2bf(tile[jj2][ll2]);
  }
}

// ---------------- GEMM1: H = [xn | xprev] @ B1cat^T  (2048 x 4096 x 320) -----
__global__ __launch_bounds__(256) void gemm1_kernel(
    const ushort_t* __restrict__ xnbf, const ushort_t* __restrict__ xprevbf,
    const ushort_t* __restrict__ B1, ushort_t* __restrict__ H)
{
  __shared__ __align__(16) ushort_t As[128 * 64];
  __shared__ __align__(16) ushort_t Bs[64 * 64];
  int tid = threadIdx.x;
  int w = tid >> 6, lane = tid & 63;
  int col0 = blockIdx.x * 64, row0 = blockIdx.y * 128;
  int quad = lane >> 4, r16 = lane & 15;
  f32x4 acc[2][4] = {};
  int lrow = lane >> 3;
  int lsw = (lane & 7) ^ lrow;

  for (int k0 = 0; k0 < 4096; k0 += 64) {
    const ushort_t* Abase = (k0 < kD) ? (xnbf + k0) : (xprevbf + (k0 - kD));
    #pragma unroll
    for (int n = 0; n < 4; n++) {
      int rr = w * 32 + n * 8 + lrow;
      const ushort_t* ga = Abase + (size_t)(row0 + rr) * kD + lsw * 8;
      __builtin_amdgcn_global_load_lds(
          (const __attribute__((address_space(1))) uint32*)ga,
          (__attribute__((address_space(3))) uint32*)&As[(w * 32 + n * 8) * 64], 16, 0, 0);
    }
    #pragma unroll
    for (int n = 0; n < 2; n++) {
      int rr = w * 16 + n * 8 + lrow;
      const ushort_t* gb = B1 + (size_t)(col0 + rr) * 4096 + k0 + lsw * 8;
      __builtin_amdgcn_global_load_lds(
          (const __attribute__((address_space(1))) uint32*)gb,
          (__attribute__((address_space(3))) uint32*)&Bs[(w * 16 + n * 8) * 64], 16, 0, 0);
    }
    __syncthreads();
    #pragma unroll
    for (int kk = 0; kk < 64; kk += 32) {
      bf16x8 af[2], bfr[4];
      #pragma unroll
      for (int i = 0; i < 2; i++) {
        int row = w * 32 + i * 16 + r16;
        int chunk = ((kk >> 3) + quad) ^ (r16 & 7);
        af[i] = *(const bf16x8*)&As[row * 64 + chunk * 8];
      }
      #pragma unroll
      for (int j = 0; j < 4; j++) {
        int row = j * 16 + r16;
        int chunk = ((kk >> 3) + quad) ^ (r16 & 7);
        bfr[j] = *(const bf16x8*)&Bs[row * 64 + chunk * 8];
      }
      #pragma unroll
      for (int i = 0; i < 2; i++)
        #pragma unroll
        for (int j = 0; j < 4; j++)
          acc[i][j] = __builtin_amdgcn_mfma_f32_16x16x32_bf16(af[i], bfr[j], acc[i][j], 0, 0, 0);
    }
    __syncthreads();
  }
  #pragma unroll
  for (int i = 0; i < 2; i++) {
    #pragma unroll
    for (int j = 0; j < 4; j++) {
      int col = col0 + j * 16 + r16;
      #pragma unroll
      for (int reg = 0; reg < 4; reg++) {
        int row = row0 + w * 32 + i * 16 + quad * 4 + reg;
        float v = acc[i][j][reg];
        if (col < 128) v = sigm(v);
        else if (col >= 192 && col < 256) v = tanhf(v);
        H[(size_t)row * 320 + col] = f2bf(v);
      }
    }
  }
}

// ---------------- GEMM2 (z-batched, K=Lz): out = act(H_z @ W2_z + bias) ------
struct Gemm2Args {
  const ushort_t* H;
  const ushort_t* B2[4];
  int Aofs[4];
  int L[4];
  const float* bias[4];
  float* out[4];
  const float* vfirst;
};
__global__ __launch_bounds__(256) void gemm2_kernel(Gemm2Args a)
{
  int z = blockIdx.z;
  int L = a.L[z];
  int nch = L >> 3;
  int rs = __builtin_ctz(nch);
  int mask = (nch >= 8) ? 7 : (nch - 1);
  __shared__ __align__(16) ushort_t As[128 * 128];
  __shared__ __align__(16) ushort_t Bs[128 * 128];
  int tid = threadIdx.x;
  int w = tid >> 6, lane = tid & 63;
  int row0 = blockIdx.y * 128, col0 = blockIdx.x * 128;
  int wrow = (w >> 1) * 64, wcol = (w & 1) * 64;
  int quad = lane >> 4, r16 = lane & 15;
  const ushort_t* A = a.H + a.Aofs[z];
  const ushort_t* B = a.B2[z];

  int nld = (128 * nch) >> 8;
  for (int i = 0; i < nld; i++) {
    int c = i * 256 + w * 64 + lane;
    int row = c >> rs;
    int ch = c & (nch - 1);
    int gch = ch ^ (row & mask);
    __builtin_amdgcn_global_load_lds(
        (const __attribute__((address_space(1))) uint32*)(A + (size_t)(row0 + row) * 320 + gch * 8),
        (__attribute__((address_space(3))) uint32*)&As[(i * 256 + w * 64) * 8], 16, 0, 0);
    __builtin_amdgcn_global_load_lds(
        (const __attribute__((address_space(1))) uint32*)(B + (size_t)(col0 + row) * L + gch * 8),
        (__attribute__((address_space(3))) uint32*)&Bs[(i * 256 + w * 64) * 8], 16, 0, 0);
  }
  __syncthreads();

  f32x4 acc[4][4] = {};
  int ksteps = L >> 5;
  for (int ks = 0; ks < ksteps; ks++) {
    bf16x8 af[4], bfr[4];
    #pragma unroll
    for (int i = 0; i < 4; i++) {
      int row = wrow + i * 16 + r16;
      int slot = ((ks << 2) + quad) ^ (r16 & mask);
      af[i] = *(const bf16x8*)&As[row * L + slot * 8];
    }
    #pragma unroll
    for (int j = 0; j < 4; j++) {
      int row = wcol + j * 16 + r16;
      int slot = ((ks << 2) + quad) ^ (r16 & mask);
      bfr[j] = *(const bf16x8*)&Bs[row * L + slot * 8];
    }
    #pragma unroll
    for (int i = 0; i < 4; i++)
      #pragma unroll
      for (int j = 0; j < 4; j++)
        acc[i][j] = __builtin_amdgcn_mfma_f32_16x16x32_bf16(af[i], bfr[j], acc[i][j], 0, 0, 0);
  }

  const float* bias = a.bias[z];
  float* C = a.out[z];
  #pragma unroll
  for (int i = 0; i < 4; i++) {
    #pragma unroll
    for (int j = 0; j < 4; j++) {
      int col = col0 + wcol + j * 16 + r16;
      #pragma unroll
      for (int reg = 0; reg < 4; reg++) {
        int row = row0 + wrow + i * 16 + quad * 4 + reg;
        float s = acc[i][j][reg];
        size_t idx = (size_t)row * kD + col;
        if (z == 0) {
          C[idx] = s;
        } else if (z == 1) {
          C[idx] = sigm(s + bias[col]);
        } else if (z == 2) {
          C[idx] = __expf(-0.606531f * sigm(s + bias[col]));
        } else {
          float vv = C[idx];
          C[idx] = vv + (a.vfirst[idx] - vv) * sigm(s + bias[col]);
        }
      }
    }
  }
}

// ---------------- post: kk(neg), k update, b, wr in-place, c1/c2/c3 ----------
__global__ __launch_bounds__(256) void post_kernel(
    float* __restrict__ kArr, float* __restrict__ kkArr, float* __restrict__ bArr,
    const float* __restrict__ aArr, float* __restrict__ rArr, const float* __restrict__ wArr,
    const float* __restrict__ k_k, const float* __restrict__ k_a, const float* __restrict__ r_k,
    float* __restrict__ c12, float* __restrict__ c3)
{
  int gid = blockIdx.x * 4 + (threadIdx.x >> 6);   // t*H + h
  int lane = threadIdx.x & 63;
  int h = gid & (kH - 1);
  int d = h * kN + lane;
  size_t off = (size_t)gid * kN + lane;
  float kv = kArr[off];
  float kkv = kv * k_k[d];
  float ss = kkv * kkv;
  #pragma unroll
  for (int o = 32; o > 0; o >>= 1) ss += __shfl_xor(ss, o);
  float scale = 1.f / fmaxf(sqrtf(ss), 1e-12f);
  float kkf = kkv * scale;
  kkArr[off] = -kkf;                 // pre-negated for the scan
  float av = aArr[off];
  float bv = kkf * av;
  bArr[off] = bv;
  float knew = kv * (1.f + (av - 1.f) * k_a[d]);
  kArr[off] = knew;
  float rv = rArr[off];
  float wv = wArr[off];
  rArr[off] = wv * rv;               // in-place wr
  float p1 = bv * rv;
  float p2 = knew * rv;
  float p3 = rv * knew * r_k[d];
  #pragma unroll
  for (int o = 32; o > 0; o >>= 1) {
    p1 += __shfl_xor(p1, o); p2 += __shfl_xor(p2, o); p3 += __shfl_xor(p3, o);
  }
  if (lane == 0) {
    c12[(size_t)gid * 2]     = p1;
    c12[(size_t)gid * 2 + 1] = p2;
    c3[gid] = p3;
  }
}

// ---------------- sequential scan: producer/consumer + single DPP reduce -----
// y_i decoupled: y_i = u_i + sa_i*c1 + v_i*c2 with u_i = dot(s_old, w*r).
// Both dots (sa, u) share one interleaved 4-stage DPP pass. kk is pre-negated.
#define SLOT_F 344   // 5*64 vectors + 16 v + 2 c + pad
#define NSLOT 24

__device__ __forceinline__ void row_allsum2(float& x, float& y) {
  int t;
  t = __builtin_amdgcn_update_dpp(0, __float_as_int(x), 0x121, 0xF, 0xF, true);
  x += __int_as_float(t);
  t = __builtin_amdgcn_update_dpp(0, __float_as_int(y), 0x121, 0xF, 0xF, true);
  y += __int_as_float(t);
  t = __builtin_amdgcn_update_dpp(0, __float_as_int(x), 0x122, 0xF, 0xF, true);
  x += __int_as_float(t);
  t = __builtin_amdgcn_update_dpp(0, __float_as_int(y), 0x122, 0xF, 0xF, true);
  y += __int_as_float(t);
  t = __builtin_amdgcn_update_dpp(0, __float_as_int(x), 0x124, 0xF, 0xF, true);
  x += __int_as_float(t);
  t = __builtin_amdgcn_update_dpp(0, __float_as_int(y), 0x124, 0xF, 0xF, true);
  y += __int_as_float(t);
  t = __builtin_amdgcn_update_dpp(0, __float_as_int(x), 0x128, 0xF, 0xF, true);
  x += __int_as_float(t);
  t = __builtin_amdgcn_update_dpp(0, __float_as_int(y), 0x128, 0xF, 0xF, true);
  y += __int_as_float(t);
}

__global__ __launch_bounds__(320) void scan_kernel(
    const float* __restrict__ s0_in, const float* __restrict__ wA, const float* __restrict__ wrA,
    const float* __restrict__ kA, const float* __restrict__ vA, const float* __restrict__ kkA,
    const float* __restrict__ bA, const float* __restrict__ c12,
    float* __restrict__ y, float* __restrict__ s_out)
{
  __shared__ __align__(16) float ring[NSLOT * SLOT_F];
  int blk = blockIdx.x;
  int h = blk >> 2;
  int i0 = (blk & 3) << 4;
  int wid = threadIdx.x >> 6;
  int lane = threadIdx.x & 63;
  int hv = h * kN;

  if (wid == 0) {
    const float* src0 = wA + hv;
    const float* src1 = wrA + hv;
    const float* src2 = kA + hv;
    const float* src3 = kkA + hv;
    const float* src4 = bA + hv;
    const float* vsrc = vA + hv + i0;
    const float* csrc = c12 + (size_t)h * 2;
    int slot = 0;
    #define ISSUE(t)                                                                     \
      {                                                                                  \
        float* sb = &ring[slot * SLOT_F];                                                \
        size_t go = (size_t)(t) * kD + lane;                                             \
        __builtin_amdgcn_global_load_lds(                                                \
            (const __attribute__((address_space(1))) uint32*)(src0 + go),                \
            (__attribute__((address_space(3))) uint32*)(sb + 0), 4, 0, 0);               \
        __builtin_amdgcn_global_load_lds(                                                \
            (const __attribute__((address_space(1))) uint32*)(src1 + go),                \
            (__attribute__((address_space(3))) uint32*)(sb + 64), 4, 0, 0);              \
        __builtin_amdgcn_global_load_lds(                                                \
            (const __attribute__((address_space(1))) uint32*)(src2 + go),                \
            (__attribute__((address_space(3))) uint32*)(sb + 128), 4, 0, 0);             \
        __builtin_amdgcn_global_load_lds(                                                \
            (const __attribute__((address_space(1))) uint32*)(src3 + go),                \
            (__attribute__((address_space(3))) uint32*)(sb + 192), 4, 0, 0);             \
        __builtin_amdgcn_global_load_lds(                                                \
            (const __attribute__((address_space(1))) uint32*)(src4 + go),                \
            (__attribute__((address_space(3))) uint32*)(sb + 256), 4, 0, 0);             \
        if (lane < 16)                                                                   \
          __builtin_amdgcn_global_load_lds(                                              \
              (const __attribute__((address_space(1))) uint32*)(vsrc + (size_t)(t) * kD + lane), \
              (__attribute__((address_space(3))) uint32*)(sb + 320), 4, 0, 0);           \
        if (lane < 2)                                                                    \
          __builtin_amdgcn_global_load_lds(                                              \
              (const __attribute__((address_space(1))) uint32*)(csrc + (size_t)(t) * (kH * 2) + lane), \
              (__attribute__((address_space(3))) uint32*)(sb + 336), 4, 0, 0);           \
        slot++; if (slot == NSLOT) slot = 0;                                             \
      }
    for (int t = 0; t < 16; t++) ISSUE(t);
    __syncthreads();
    for (int ph = 0; ph < kS / 8; ph++) {
      int t0 = ph * 8 + 16;
      if (t0 < kS) {
        for (int s = 0; s < 8; s++) ISSUE(t0 + s);
      }
      __syncthreads();
    }
    #undef ISSUE
  } else {
    int col16 = lane & 15;
    int row = lane >> 4;
    int vidx = (wid - 1) * 4 + row;
    int i = i0 + vidx;
    int co = col16 * 4;
    size_t srow = ((size_t)(hv + i)) * kN + co;
    float4 sS = *(const float4*)(s0_in + srow);
    float* py = y + (size_t)(hv + i);

    __syncthreads();

    float4 Aw4, Awr4, Ak4, Akk4, Ab4; float Av1, Ac1, Ac2;
    float4 Bw4, Bwr4, Bk4, Bkk4, Bb4; float Bv1, Bc1, Bc2;

    #define LOADSLOT(sl, W, WR, K, KK, B, V, C1, C2)             \
      {                                                          \
        const float* sb = &ring[(sl) * SLOT_F];                  \
        W  = *(const float4*)(sb + co);                          \
        WR = *(const float4*)(sb + 64 + co);                     \
        K  = *(const float4*)(sb + 128 + co);                    \
        KK = *(const float4*)(sb + 192 + co);                    \
        B  = *(const float4*)(sb + 256 + co);                    \
        V  = sb[320 + vidx];                                     \
        C1 = sb[336];                                            \
        C2 = sb[337];                                            \
      }
    #define STEP(W, WR, K, KK, B, V, C1, C2)                                  \
      {                                                                       \
        float sa = sS.x * KK.x + sS.y * KK.y + sS.z * KK.z + sS.w * KK.w;     \
        float u  = sS.x * WR.x + sS.y * WR.y + sS.z * WR.z + sS.w * WR.w;     \
        row_allsum2(sa, u);                                                   \
        sS.x = fmaf(sS.x, W.x, fmaf(sa, B.x, V * K.x));                       \
        sS.y = fmaf(sS.y, W.y, fmaf(sa, B.y, V * K.y));                       \
        sS.z = fmaf(sS.z, W.z, fmaf(sa, B.z, V * K.z));                       \
        sS.w = fmaf(sS.w, W.w, fmaf(sa, B.w, V * K.w));                       \
        float yv = fmaf(sa, C1, fmaf(V, C2, u));                              \
        if (col16 == 0) *py = yv;                                             \
        py += kD;                                                             \
      }

    LOADSLOT(0, Aw4, Awr4, Ak4, Akk4, Ab4, Av1, Ac1, Ac2);
    int slot = 1;
    for (int ph = 0; ph < kS / 8; ph++) {
      #pragma unroll
      for (int s = 0; s < 8; s += 2) {
        LOADSLOT(slot, Bw4, Bwr4, Bk4, Bkk4, Bb4, Bv1, Bc1, Bc2);
        slot++; if (slot == NSLOT) slot = 0;
        STEP(Aw4, Awr4, Ak4, Akk4, Ab4, Av1, Ac1, Ac2);
        LOADSLOT(slot, Aw4, Awr4, Ak4, Akk4, Ab4, Av1, Ac1, Ac2);
        slot++; if (slot == NSLOT) slot = 0;
        STEP(Bw4, Bwr4, Bk4, Bkk4, Bb4, Bv1, Bc1, Bc2);
      }
      __syncthreads();
    }
    #undef LOADSLOT
    #undef STEP
    *(float4*)(s_out + srow) = sS;
  }
}

// ---------------- output: groupnorm(y)*lnx + c3*v, *gate → bf16 A for Wo -----
__global__ __launch_bounds__(256) void out_kernel(
    const float* __restrict__ y, const float* __restrict__ vA, const float* __restrict__ c3,
    const float* __restrict__ lnw, const float* __restrict__ lnb,
    const float* __restrict__ gate, ushort_t* __restrict__ Ay)
{
  int gid = blockIdx.x * 4 + (threadIdx.x >> 6);
  int lane = threadIdx.x & 63;
  int h = gid & (kH - 1);
  size_t off = (size_t)gid * kN + lane;
  float yv = y[off];
  float s = yv, s2 = yv * yv;
  #pragma unroll
  for (int o = 32; o > 0; o >>= 1) { s += __shfl_xor(s, o); s2 += __shfl_xor(s2, o); }
  float mean = s * (1.f / kN);
  float var = s2 * (1.f / kN) - mean * mean;
  float o1 = (yv - mean) * rsqrtf(var + 0.00064f);
  int d = h * kN + lane;
  float ov = o1 * lnw[d] + lnb[d];
  float rkv = c3[gid] * vA[off];
  Ay[off] = f2bf((ov + rkv) * gate[off]);
}

extern "C" void kernel_launch(void* const* d_in, const int* in_sizes, int n_in,
                              void* d_out, int out_size, void* d_ws, size_t ws_size,
                              hipStream_t stream)
{
  const float* x      = (const float*)d_in[0];
  const float* state1 = (const float*)d_in[1];
  const float* state2 = (const float*)d_in[2];
  const float* vfirst = (const float*)d_in[3];
  const float* ln1w   = (const float*)d_in[4];
  const float* ln1b   = (const float*)d_in[5];
  const float* xr_c   = (const float*)d_in[6];
  const float* xw_c   = (const float*)d_in[7];
  const float* xk_c   = (const float*)d_in[8];
  const float* xv_c   = (const float*)d_in[9];
  const float* xa_c   = (const float*)d_in[10];
  const float* xg_c   = (const float*)d_in[11];
  const float* Wr     = (const float*)d_in[12];
  const float* Wk     = (const float*)d_in[13];
  const float* Wv     = (const float*)d_in[14];
  const float* Wo     = (const float*)d_in[15];
  const float* w1     = (const float*)d_in[16];
  const float* w2     = (const float*)d_in[17];
  const float* w0     = (const float*)d_in[18];
  const float* a1     = (const float*)d_in[19];
  const float* a2     = (const float*)d_in[20];
  const float* a0     = (const float*)d_in[21];
  const float* g1     = (const float*)d_in[22];
  const float* g2     = (const float*)d_in[23];
  const float* v1     = (const float*)d_in[24];
  const float* v2     = (const float*)d_in[25];
  const float* v0     = (const float*)d_in[26];
  const float* k_k    = (const float*)d_in[27];
  const float* k_a    = (const float*)d_in[28];
  const float* r_k    = (const float*)d_in[29];
  const float* lnxw   = (const float*)d_in[30];
  const float* lnxb   = (const float*)d_in[31];

  float* out0  = (float*)d_out;
  float* s1out = out0 + (size_t)kS * kD;
  float* s2out = s1out + kD;

  size_t SD = (size_t)kS * kD;
  float* ws  = (float*)d_ws;
  float* xnB = ws;                 // bf16 xn + bf16 xprev; c12/c3 after gemm1
  float* rB  = ws + SD;
  float* kB  = ws + 2 * SD;
  float* vB  = ws + 3 * SD;
  float* wB  = ws + 4 * SD;
  float* aB  = ws + 5 * SD;
  float* kkB = ws + 6 * SD;
  float* bB  = ws + 7 * SD;
  float* gB  = ws + 8 * SD;
  float* yB  = ws + 9 * SD;

  ushort_t* xnbf    = (ushort_t*)xnB;
  ushort_t* xprevbf = (ushort_t*)xnB + SD;
  ushort_t* ArB = (ushort_t*)kkB;        // dead before post writes kkB
  ushort_t* AkB = (ushort_t*)kkB + SD;
  ushort_t* AvB = (ushort_t*)bB;         // bB first half
  ushort_t* B1  = (ushort_t*)bB + SD;    // bB second half: B1 | H | B2
  ushort_t* Hbuf = B1 + (size_t)320 * 4096;
  ushort_t* B2g  = Hbuf + (size_t)2048 * 320;
  ushort_t* B2a  = B2g + (size_t)2048 * 128;
  ushort_t* B2w  = B2a + (size_t)2048 * 64;
  ushort_t* B2v  = B2w + (size_t)2048 * 64;
  ushort_t* WrB = (ushort_t*)yB;         // dead before scan writes yB
  ushort_t* WkB = (ushort_t*)yB + SD;
  ushort_t* WvB = (ushort_t*)gB;         // dead before gemm2 writes gB
  ushort_t* AyB = (ushort_t*)aB;         // aB dead after post
  ushort_t* WoB = (ushort_t*)rB;         // rB (wr) dead after scan
  // c12/c3 live in the xn region (dead after gemm1, before post)
  float* c12B = xnB;
  float* c3B  = xnB + (size_t)kS * kH * 2;

  ln1_kernel<<<kS, 256, 0, stream>>>(x, ln1w, ln1b, xnbf, xprevbf, state1, s1out);
  mix3_cvt<<<kS, 256, 0, stream>>>(xnbf, xprevbf, xr_c, xk_c, xv_c, ArB, AkB, AvB);

  const int CVT_BLKS = (int)(SD / 4 / 256);
  {
    CvtArgs ca;
    ca.src[0] = Wr; ca.src[1] = Wk; ca.src[2] = Wv;
    ca.dst[0] = WrB; ca.dst[1] = WkB; ca.dst[2] = WvB;
    cvt_bf16_b<<<dim3(CVT_BLKS, 3), 256, 0, stream>>>(ca);
  }
  {
    PrepW1Args pa;
    pa.w1[0] = g1; pa.w1[1] = a1; pa.w1[2] = w1; pa.w1[3] = v1;
    pa.c[0] = xg_c; pa.c[1] = xa_c; pa.c[2] = xw_c; pa.c[3] = xv_c;
    pa.B1 = B1;
    prep_w1<<<dim3(64, 20), 256, 0, stream>>>(pa);
  }
  {
    PrepW2Args pa;
    pa.w2[0] = g2; pa.w2[1] = a2; pa.w2[2] = w2; pa.w2[3] = v2;
    pa.B2[0] = B2g; pa.B2[1] = B2a; pa.B2[2] = B2w; pa.B2[3] = B2v;
    pa.L[0] = 128; pa.L[1] = 64; pa.L[2] = 64; pa.L[3] = 32;
    prep_w2<<<dim3(32, 8, 4), 256, 0, stream>>>(pa);
  }
  {
    GemmArgs ga;
    ga.A[0] = ArB; ga.A[1] = AkB; ga.A[2] = AvB;
    ga.B[0] = WrB; ga.B[1] = WkB; ga.B[2] = WvB;
    ga.C[0] = rB;  ga.C[1] = kB;  ga.C[2] = vB;
    ga.resid[0] = nullptr; ga.resid[1] = nullptr; ga.resid[2] = nullptr;
    gemm_bf16_b<<<dim3(16, 16, 3), 256, 0, stream>>>(ga);
  }

  gemm1_kernel<<<dim3(5, 16), 256, 0, stream>>>(xnbf, xprevbf, B1, Hbuf);
  {
    Gemm2Args ga;
    ga.H = Hbuf;
    ga.B2[0] = B2g; ga.B2[1] = B2a; ga.B2[2] = B2w; ga.B2[3] = B2v;
    ga.Aofs[0] = 0; ga.Aofs[1] = 128; ga.Aofs[2] = 192; ga.Aofs[3] = 256;
    ga.L[0] = 128; ga.L[1] = 64; ga.L[2] = 64; ga.L[3] = 32;
    ga.bias[0] = nullptr; ga.bias[1] = a0; ga.bias[2] = w0; ga.bias[3] = v0;
    ga.out[0] = gB; ga.out[1] = aB; ga.out[2] = wB; ga.out[3] = vB;
    ga.vfirst = vfirst;
    gemm2_kernel<<<dim3(16, 16, 4), 256, 0, stream>>>(ga);
  }

  post_kernel<<<kS * kH / 4, 256, 0, stream>>>(kB, kkB, bB, aB, rB, wB,
                                               k_k, k_a, r_k, c12B, c3B);

  scan_kernel<<<kH * 4, 320, 0, stream>>>(state2, wB, rB, kB, vB, kkB, bB, c12B, yB, s2out);

  out_kernel<<<kS * kH / 4, 256, 0, stream>>>(yB, vB, c3B, lnxw, lnxb, gB, AyB);

  {
    CvtArgs ca;
    ca.src[0] = Wo; ca.src[1] = Wo; ca.src[2] = Wo;
    ca.dst[0] = WoB; ca.dst[1] = WoB; ca.dst[2] = WoB;
    cvt_bf16_b<<<dim3(CVT_BLKS, 1), 256, 0, stream>>>(ca);
  }
  {
    GemmArgs ga;
    ga.A[0] = AyB; ga.A[1] = AyB; ga.A[2] = AyB;
    ga.B[0] = WoB; ga.B[1] = WoB; ga.B[2] = WoB;
    ga.C[0] = out0; ga.C[1] = out0; ga.C[2] = out0;
    ga.resid[0] = x; ga.resid[1] = x; ga.resid[2] = x;
    gemm_bf16_b<<<dim3(16, 16, 1), 256, 0, stream>>>(ga);
  }
}